// Round 2
// baseline (936.742 us; speedup 1.0000x reference)
//
#include <hip/hip_runtime.h>
#include <stdint.h>

#define NMET 20000
#define NRXN 40000
#define DDIM 256
#define CDIM 64

// ---------------- threefry2x32 (exact JAX semantics) ----------------
__host__ __device__ inline void tf2x32(unsigned k0, unsigned k1,
                                       unsigned x0, unsigned x1,
                                       unsigned &o0, unsigned &o1) {
  unsigned ks2 = k0 ^ k1 ^ 0x1BD11BDAu;
#define TFR(r) { x0 += x1; x1 = (x1 << r) | (x1 >> (32 - r)); x1 ^= x0; }
  x0 += k0; x1 += k1;
  TFR(13) TFR(15) TFR(26) TFR(6)
  x0 += k1; x1 += ks2 + 1u;
  TFR(17) TFR(29) TFR(16) TFR(24)
  x0 += ks2; x1 += k0 + 2u;
  TFR(13) TFR(15) TFR(26) TFR(6)
  x0 += k0; x1 += k1 + 3u;
  TFR(17) TFR(29) TFR(16) TFR(24)
  x0 += k1; x1 += ks2 + 4u;
  TFR(13) TFR(15) TFR(26) TFR(6)
  x0 += ks2; x1 += k0 + 5u;
#undef TFR
  o0 = x0; o1 = x1;
}

// ordered-uint encoding of float for atomicMax
__device__ inline unsigned fenc(float f) {
  unsigned b = __float_as_uint(f);
  return (b & 0x80000000u) ? ~b : (b | 0x80000000u);
}
__device__ inline float fdec(unsigned u) {
  unsigned b = (u & 0x80000000u) ? (u & 0x7FFFFFFFu) : ~u;
  return __uint_as_float(b);
}

// ---------------- GEMM: Y[N,Cout] = X[N,256] @ W[256,Cout] + bias ----------------
__global__ __launch_bounds__(256) void gemm_bias(
    const float* __restrict__ X, const float* __restrict__ W,
    const float* __restrict__ bias, float* __restrict__ Y,
    int N, int Cout) {
  __shared__ float As[16][68];
  __shared__ float Bs[16][68];
  const int tid = threadIdx.x;
  const int m0 = blockIdx.x * 64;
  const int n0 = blockIdx.y * 64;
  const int ty = tid >> 4, tx = tid & 15;
  const int lm = tid >> 2, lk4 = (tid & 3) << 2;
  const int lkb = tid >> 4, lnb = (tid & 15) << 2;
  float acc[4][4] = {};
  for (int kt = 0; kt < 256; kt += 16) {
    float4 av = make_float4(0.f, 0.f, 0.f, 0.f);
    if (m0 + lm < N)
      av = *reinterpret_cast<const float4*>(X + (size_t)(m0 + lm) * DDIM + kt + lk4);
    As[lk4 + 0][lm] = av.x; As[lk4 + 1][lm] = av.y;
    As[lk4 + 2][lm] = av.z; As[lk4 + 3][lm] = av.w;
    float4 bv = *reinterpret_cast<const float4*>(W + (size_t)(kt + lkb) * Cout + n0 + lnb);
    Bs[lkb][lnb + 0] = bv.x; Bs[lkb][lnb + 1] = bv.y;
    Bs[lkb][lnb + 2] = bv.z; Bs[lkb][lnb + 3] = bv.w;
    __syncthreads();
#pragma unroll
    for (int kk = 0; kk < 16; ++kk) {
      float a[4], b[4];
#pragma unroll
      for (int i = 0; i < 4; ++i) a[i] = As[kk][ty * 4 + i];
#pragma unroll
      for (int j = 0; j < 4; ++j) b[j] = Bs[kk][tx * 4 + j];
#pragma unroll
      for (int i = 0; i < 4; ++i)
#pragma unroll
        for (int j = 0; j < 4; ++j) acc[i][j] = fmaf(a[i], b[j], acc[i][j]);
    }
    __syncthreads();
  }
#pragma unroll
  for (int i = 0; i < 4; ++i) {
    int r = m0 + ty * 4 + i;
    if (r < N) {
#pragma unroll
      for (int j = 0; j < 4; ++j) {
        int c = n0 + tx * 4 + j;
        Y[(size_t)r * Cout + c] = acc[i][j] + bias[c];
      }
    }
  }
}

// ---------------- fill u32 (init segment-max to enc(-inf)) ----------------
__global__ void fill_u32(unsigned* __restrict__ p, unsigned v, int n) {
  int i = blockIdx.x * blockDim.x + threadIdx.x;
  if (i < n) p[i] = v;
}

// ---------------- edge scores + segment max ----------------
// one wave (64 lanes) per edge; lane = channel c; 4 heads
__global__ __launch_bounds__(256) void edge_scores(
    const float* __restrict__ xl, const float* __restrict__ xr,
    const int* __restrict__ src_arr, const int* __restrict__ dst_arr,
    int E_main, int n_total, const float* __restrict__ att,
    float* __restrict__ e_out, unsigned* __restrict__ m_ord) {
  int w = blockIdx.x * 4 + (threadIdx.x >> 6);
  int lane = threadIdx.x & 63;
  if (w >= n_total) return;
  int s, d;
  if (w < E_main) { s = src_arr[w]; d = dst_arr[w]; }
  else { s = d = w - E_main; }  // self loop
  const float* pl = xl + (size_t)s * DDIM;
  const float* pr = xr + (size_t)d * DDIM;
  float v[4];
#pragma unroll
  for (int h = 0; h < 4; ++h) {
    float t = pl[h * 64 + lane] + pr[h * 64 + lane];
    t = (t >= 0.f) ? t : 0.2f * t;  // leaky_relu 0.2
    v[h] = t * att[h * 64 + lane];
  }
#pragma unroll
  for (int off = 32; off; off >>= 1) {
    v[0] += __shfl_xor(v[0], off);
    v[1] += __shfl_xor(v[1], off);
    v[2] += __shfl_xor(v[2], off);
    v[3] += __shfl_xor(v[3], off);
  }
  if (lane == 0) {
#pragma unroll
    for (int h = 0; h < 4; ++h) {
      e_out[(size_t)w * 4 + h] = v[h];
      atomicMax(&m_ord[(size_t)d * 4 + h], fenc(v[h]));
    }
  }
}

// ---------------- exp(e - m[dst]) in place + denominator ----------------
__global__ __launch_bounds__(256) void edge_softmax_den(
    float* __restrict__ e_inout, const int* __restrict__ dst_arr,
    int E_main, int n_total, const unsigned* __restrict__ m_ord,
    float* __restrict__ den) {
  int i = blockIdx.x * blockDim.x + threadIdx.x;
  if (i >= n_total * 4) return;
  int w = i >> 2, h = i & 3;
  int d = (w < E_main) ? dst_arr[w] : (w - E_main);
  float m = fdec(m_ord[(size_t)d * 4 + h]);
  float ex = expf(e_inout[i] - m);
  e_inout[i] = ex;
  atomicAdd(&den[(size_t)d * 4 + h], ex);
}

// ---------------- aggregate: acc[dst,c] += (1/4) sum_h alpha_h * xl[src,h*64+c] ----------------
__global__ __launch_bounds__(256) void edge_aggregate(
    const float* __restrict__ xl, const float* __restrict__ ex,
    const float* __restrict__ den, const int* __restrict__ src_arr,
    const int* __restrict__ dst_arr, int E_main, int n_total,
    float* __restrict__ acc) {
  int w = blockIdx.x * 4 + (threadIdx.x >> 6);
  int lane = threadIdx.x & 63;
  if (w >= n_total) return;
  int s, d;
  if (w < E_main) { s = src_arr[w]; d = dst_arr[w]; }
  else { s = d = w - E_main; }
  float a[4];
#pragma unroll
  for (int h = 0; h < 4; ++h)
    a[h] = ex[(size_t)w * 4 + h] / (den[(size_t)d * 4 + h] + 1e-16f);
  const float* pl = xl + (size_t)s * DDIM;
  float v = a[0] * pl[lane] + a[1] * pl[64 + lane] +
            a[2] * pl[128 + lane] + a[3] * pl[192 + lane];
  atomicAdd(&acc[(size_t)d * 64 + lane], 0.25f * v);
}

// ---------------- finalize: elu + residual(proj in out) + LN + threefry dropout ----------------
// Dropout follows jax_threefry_partitionable=True semantics:
//   bits[i] = o0 ^ o1 where (o0,o1) = threefry2x32(key, (0, i))
__global__ __launch_bounds__(256) void finalize(
    const float* __restrict__ acc, float* __restrict__ out,
    const float* __restrict__ bA, const float* __restrict__ bB, float scale,
    const float* __restrict__ g, const float* __restrict__ beta,
    int Nn, unsigned key0, unsigned key1) {
  int w = blockIdx.x * 4 + (threadIdx.x >> 6);
  int lane = threadIdx.x & 63;
  if (w >= Nn) return;
  unsigned idx = (unsigned)w * 64u + (unsigned)lane;
  float bias = bA[lane] + (bB ? bB[lane] : 0.f);
  float pre = scale * (acc[idx] + bias);
  pre = (pre > 0.f) ? pre : expm1f(pre);      // elu
  pre += out[idx];                             // + proj (bias already added)
  // LayerNorm over 64 lanes
  float mu = pre;
#pragma unroll
  for (int off = 32; off; off >>= 1) mu += __shfl_xor(mu, off);
  mu *= (1.0f / 64.0f);
  float dv = pre - mu;
  float var = dv * dv;
#pragma unroll
  for (int off = 32; off; off >>= 1) var += __shfl_xor(var, off);
  var *= (1.0f / 64.0f);
  float y = dv * rsqrtf(var + 1e-5f) * g[lane] + beta[lane];
  // threefry dropout (partitionable), keep-prob 0.8
  unsigned o0, o1;
  tf2x32(key0, key1, 0u, idx, o0, o1);
  unsigned bits = o0 ^ o1;
  float u = __uint_as_float((bits >> 9) | 0x3f800000u) - 1.0f;
  y = (u < 0.8f) ? y / 0.8f : 0.0f;
  out[idx] = y;
}

// ---------------- launch ----------------
extern "C" void kernel_launch(void* const* d_in, const int* in_sizes, int n_in,
                              void* d_out, int out_size, void* d_ws, size_t ws_size,
                              hipStream_t stream) {
  const float* x_met = (const float*)d_in[0];
  const float* x_rxn = (const float*)d_in[1];
  const int* sub_src = (const int*)d_in[2];
  const int* sub_dst = (const int*)d_in[3];
  const int* prod_src = (const int*)d_in[4];
  const int* prod_dst = (const int*)d_in[5];
  const int* shr_src = (const int*)d_in[6];
  const int* shr_dst = (const int*)d_in[7];
  const float* Wl_sub = (const float*)d_in[8];
  const float* bl_sub = (const float*)d_in[9];
  const float* Wr_sub = (const float*)d_in[10];
  const float* br_sub = (const float*)d_in[11];
  const float* att_sub = (const float*)d_in[12];
  const float* b_sub = (const float*)d_in[13];
  const float* Wl_prod = (const float*)d_in[14];
  const float* bl_prod = (const float*)d_in[15];
  const float* Wr_prod = (const float*)d_in[16];
  const float* br_prod = (const float*)d_in[17];
  const float* att_prod = (const float*)d_in[18];
  const float* b_prod = (const float*)d_in[19];
  const float* Wl_shr = (const float*)d_in[20];
  const float* bl_shr = (const float*)d_in[21];
  const float* Wr_shr = (const float*)d_in[22];
  const float* br_shr = (const float*)d_in[23];
  const float* att_shr = (const float*)d_in[24];
  const float* b_shr = (const float*)d_in[25];
  const float* W_proj_rxn = (const float*)d_in[26];
  const float* b_proj_rxn = (const float*)d_in[27];
  const float* W_proj_met = (const float*)d_in[28];
  const float* b_proj_met = (const float*)d_in[29];
  const float* ln_rxn_g = (const float*)d_in[30];
  const float* ln_rxn_b = (const float*)d_in[31];
  const float* ln_met_g = (const float*)d_in[32];
  const float* ln_met_b = (const float*)d_in[33];

  const int E = in_sizes[2];                 // 250000
  const int E_shr = E + NRXN;                // with self loops

  // workspace carve (floats)
  float* ws = (float*)d_ws;
  float* xl_buf = ws;                                  // 40000*256
  float* xr_buf = xl_buf + (size_t)NRXN * DDIM;        // 40000*256
  float* e_buf  = xr_buf + (size_t)NRXN * DDIM;        // 290000*4 max
  unsigned* m_buf = (unsigned*)(e_buf + (size_t)(E_shr) * 4);
  float* den_buf = (float*)(m_buf + (size_t)NRXN * 4);
  float* acc_rxn = den_buf + (size_t)NRXN * 4;         // 40000*64
  float* acc_met = acc_rxn + (size_t)NRXN * CDIM;      // 20000*64

  float* out_rxn = (float*)d_out;                      // 40000*64
  float* out_met = out_rxn + (size_t)NRXN * CDIM;      // 20000*64

  // host-side threefry split (partitionable=True foldlike):
  //   subkey i = threefry2x32(key, (0, i)); key(1) = (0,1)
  unsigned k1_0, k1_1, k2_0, k2_1;
  tf2x32(0u, 1u, 0u, 0u, k1_0, k1_1);   // k1 (rxn dropout)
  tf2x32(0u, 1u, 0u, 1u, k2_0, k2_1);   // k2 (met dropout)

  hipMemsetAsync(acc_rxn, 0, (size_t)NRXN * CDIM * sizeof(float), stream);
  hipMemsetAsync(acc_met, 0, (size_t)NMET * CDIM * sizeof(float), stream);

  dim3 blk(256);
  // projection GEMMs directly into d_out (scratch until finalize overwrites)
  gemm_bias<<<dim3((NRXN + 63) / 64, CDIM / 64), blk, 0, stream>>>(
      x_rxn, W_proj_rxn, b_proj_rxn, out_rxn, NRXN, CDIM);
  gemm_bias<<<dim3((NMET + 63) / 64, CDIM / 64), blk, 0, stream>>>(
      x_met, W_proj_met, b_proj_met, out_met, NMET, CDIM);

  const unsigned ENC_NEG_INF = 0x007FFFFFu;  // fenc(-inf)

  // ---------- relation: substrate (met -> rxn) ----------
  gemm_bias<<<dim3((NMET + 63) / 64, DDIM / 64), blk, 0, stream>>>(
      x_met, Wl_sub, bl_sub, xl_buf, NMET, DDIM);
  gemm_bias<<<dim3((NRXN + 63) / 64, DDIM / 64), blk, 0, stream>>>(
      x_rxn, Wr_sub, br_sub, xr_buf, NRXN, DDIM);
  fill_u32<<<(NRXN * 4 + 255) / 256, blk, 0, stream>>>(m_buf, ENC_NEG_INF, NRXN * 4);
  hipMemsetAsync(den_buf, 0, (size_t)NRXN * 4 * sizeof(float), stream);
  edge_scores<<<(E + 3) / 4, blk, 0, stream>>>(
      xl_buf, xr_buf, sub_src, sub_dst, E, E, att_sub, e_buf, m_buf);
  edge_softmax_den<<<(E * 4 + 255) / 256, blk, 0, stream>>>(
      e_buf, sub_dst, E, E, m_buf, den_buf);
  edge_aggregate<<<(E + 3) / 4, blk, 0, stream>>>(
      xl_buf, e_buf, den_buf, sub_src, sub_dst, E, E, acc_rxn);

  // ---------- relation: shared_metabolite (rxn -> rxn, +self loops) ----------
  gemm_bias<<<dim3((NRXN + 63) / 64, DDIM / 64), blk, 0, stream>>>(
      x_rxn, Wl_shr, bl_shr, xl_buf, NRXN, DDIM);
  gemm_bias<<<dim3((NRXN + 63) / 64, DDIM / 64), blk, 0, stream>>>(
      x_rxn, Wr_shr, br_shr, xr_buf, NRXN, DDIM);
  fill_u32<<<(NRXN * 4 + 255) / 256, blk, 0, stream>>>(m_buf, ENC_NEG_INF, NRXN * 4);
  hipMemsetAsync(den_buf, 0, (size_t)NRXN * 4 * sizeof(float), stream);
  edge_scores<<<(E_shr + 3) / 4, blk, 0, stream>>>(
      xl_buf, xr_buf, shr_src, shr_dst, E, E_shr, att_shr, e_buf, m_buf);
  edge_softmax_den<<<(E_shr * 4 + 255) / 256, blk, 0, stream>>>(
      e_buf, shr_dst, E, E_shr, m_buf, den_buf);
  edge_aggregate<<<(E_shr + 3) / 4, blk, 0, stream>>>(
      xl_buf, e_buf, den_buf, shr_src, shr_dst, E, E_shr, acc_rxn);

  // ---------- relation: product (rxn -> met) ----------
  gemm_bias<<<dim3((NRXN + 63) / 64, DDIM / 64), blk, 0, stream>>>(
      x_rxn, Wl_prod, bl_prod, xl_buf, NRXN, DDIM);
  gemm_bias<<<dim3((NMET + 63) / 64, DDIM / 64), blk, 0, stream>>>(
      x_met, Wr_prod, br_prod, xr_buf, NMET, DDIM);
  fill_u32<<<(NMET * 4 + 255) / 256, blk, 0, stream>>>(m_buf, ENC_NEG_INF, NMET * 4);
  hipMemsetAsync(den_buf, 0, (size_t)NMET * 4 * sizeof(float), stream);
  edge_scores<<<(E + 3) / 4, blk, 0, stream>>>(
      xl_buf, xr_buf, prod_src, prod_dst, E, E, att_prod, e_buf, m_buf);
  edge_softmax_den<<<(E * 4 + 255) / 256, blk, 0, stream>>>(
      e_buf, prod_dst, E, E, m_buf, den_buf);
  edge_aggregate<<<(E + 3) / 4, blk, 0, stream>>>(
      xl_buf, e_buf, den_buf, prod_src, prod_dst, E, E, acc_met);

  // ---------- finalize ----------
  finalize<<<(NRXN + 3) / 4, blk, 0, stream>>>(
      acc_rxn, out_rxn, b_sub, b_shr, 0.5f, ln_rxn_g, ln_rxn_b,
      NRXN, k1_0, k1_1);
  finalize<<<(NMET + 3) / 4, blk, 0, stream>>>(
      acc_met, out_met, b_prod, nullptr, 1.0f, ln_met_g, ln_met_b,
      NMET, k2_0, k2_1);
}

// Round 3
// 678.672 us; speedup vs baseline: 1.3803x; 1.3803x over previous
//
#include <hip/hip_runtime.h>
#include <hip/hip_bf16.h>
#include <stdint.h>

#define NMET 20000
#define NRXN 40000
#define DDIM 256
#define CDIM 64

typedef __attribute__((ext_vector_type(8))) short bf16x8;
typedef __attribute__((ext_vector_type(4))) float f32x4;

// ---------------- threefry2x32 (exact JAX semantics) ----------------
__host__ __device__ inline void tf2x32(unsigned k0, unsigned k1,
                                       unsigned x0, unsigned x1,
                                       unsigned &o0, unsigned &o1) {
  unsigned ks2 = k0 ^ k1 ^ 0x1BD11BDAu;
#define TFR(r) { x0 += x1; x1 = (x1 << r) | (x1 >> (32 - r)); x1 ^= x0; }
  x0 += k0; x1 += k1;
  TFR(13) TFR(15) TFR(26) TFR(6)
  x0 += k1; x1 += ks2 + 1u;
  TFR(17) TFR(29) TFR(16) TFR(24)
  x0 += ks2; x1 += k0 + 2u;
  TFR(13) TFR(15) TFR(26) TFR(6)
  x0 += k0; x1 += k1 + 3u;
  TFR(17) TFR(29) TFR(16) TFR(24)
  x0 += k1; x1 += ks2 + 4u;
  TFR(13) TFR(15) TFR(26) TFR(6)
  x0 += ks2; x1 += k0 + 5u;
#undef TFR
  o0 = x0; o1 = x1;
}

__device__ inline unsigned fenc(float f) {
  unsigned b = __float_as_uint(f);
  return (b & 0x80000000u) ? ~b : (b | 0x80000000u);
}
__device__ inline float fdec(unsigned u) {
  unsigned b = (u & 0x80000000u) ? (u & 0x7FFFFFFFu) : ~u;
  return __uint_as_float(b);
}

__device__ inline unsigned short f2bbits(float f) {
  __hip_bfloat16 h = __float2bfloat16(f);
  return *reinterpret_cast<unsigned short*>(&h);
}

// ---------------- fp32 -> bf16 convert (vectorized) ----------------
__global__ __launch_bounds__(256) void cvt_bf16(
    const float* __restrict__ in, __hip_bfloat16* __restrict__ out, int n) {
  int i = (blockIdx.x * 256 + threadIdx.x) * 8;
  if (i >= n) return;
  float4 a = *reinterpret_cast<const float4*>(in + i);
  float4 b = *reinterpret_cast<const float4*>(in + i + 4);
  bf16x8 o;
  o[0] = (short)f2bbits(a.x); o[1] = (short)f2bbits(a.y);
  o[2] = (short)f2bbits(a.z); o[3] = (short)f2bbits(a.w);
  o[4] = (short)f2bbits(b.x); o[5] = (short)f2bbits(b.y);
  o[6] = (short)f2bbits(b.z); o[7] = (short)f2bbits(b.w);
  *reinterpret_cast<bf16x8*>(out + i) = o;
}

// ---------------- W[k][n] -> Wt[n][k] bf16, 8 matrices fused ----------------
__global__ __launch_bounds__(256) void wtrans(
    const float* w0, const float* w1, const float* w2, const float* w3,
    const float* w4, const float* w5, const float* w6, const float* w7,
    __hip_bfloat16* o0, __hip_bfloat16* o1, __hip_bfloat16* o2, __hip_bfloat16* o3,
    __hip_bfloat16* o4, __hip_bfloat16* o5, __hip_bfloat16* o6, __hip_bfloat16* o7) {
  int z = blockIdx.y;
  const float* w; __hip_bfloat16* o; int Ncols;
  switch (z) {
    case 0: w = w0; o = o0; Ncols = 256; break;
    case 1: w = w1; o = o1; Ncols = 256; break;
    case 2: w = w2; o = o2; Ncols = 256; break;
    case 3: w = w3; o = o3; Ncols = 256; break;
    case 4: w = w4; o = o4; Ncols = 256; break;
    case 5: w = w5; o = o5; Ncols = 256; break;
    case 6: w = w6; o = o6; Ncols = 64; break;
    default: w = w7; o = o7; Ncols = 64; break;
  }
  int ntile = Ncols / 32;
  int t = blockIdx.x;
  if (t >= ntile * 8) return;  // K=256 -> 8 k-tiles
  int tn = t % ntile, tk = t / ntile;
  __shared__ float ts[32][33];
  int tx = threadIdx.x & 31, ty = threadIdx.x >> 5;  // 8 rows per iter
#pragma unroll
  for (int r = ty; r < 32; r += 8)
    ts[r][tx] = w[(size_t)(tk * 32 + r) * Ncols + tn * 32 + tx];
  __syncthreads();
#pragma unroll
  for (int r = ty; r < 32; r += 8)
    o[(size_t)(tn * 32 + r) * 256 + tk * 32 + tx] = __float2bfloat16(ts[tx][r]);
}

// ---------------- MFMA GEMM: Y[M,N] = Xb[M,256] @ Wt[N,256]^T + bias ----------------
// one wave per 64x64 output tile; A/B frags loaded straight from global.
template <typename OutT>
__global__ __launch_bounds__(256) void gemm_mfma(
    const __hip_bfloat16* __restrict__ Xb, const __hip_bfloat16* __restrict__ Wt,
    const float* __restrict__ bias, OutT* __restrict__ Y, int M, int N) {
  int wave = threadIdx.x >> 6;
  int lane = threadIdx.x & 63;
  int nt = N >> 6;
  int mt = (M + 63) >> 6;
  int tile = blockIdx.x * 4 + wave;
  if (tile >= mt * nt) return;
  int m0 = (tile / nt) * 64, n0 = (tile % nt) * 64;
  int lr = lane & 15, lk = lane >> 4;

  size_t arow[4], brow[4];
#pragma unroll
  for (int i = 0; i < 4; ++i) {
    int r = m0 + i * 16 + lr;
    if (r > M - 1) r = M - 1;
    arow[i] = (size_t)r * DDIM + lk * 8;
  }
#pragma unroll
  for (int j = 0; j < 4; ++j)
    brow[j] = (size_t)(n0 + j * 16 + lr) * DDIM + lk * 8;

  f32x4 acc[4][4] = {};
#pragma unroll
  for (int kt = 0; kt < 8; ++kt) {
    bf16x8 a[4], b[4];
#pragma unroll
    for (int i = 0; i < 4; ++i)
      a[i] = *reinterpret_cast<const bf16x8*>(Xb + arow[i] + kt * 32);
#pragma unroll
    for (int j = 0; j < 4; ++j)
      b[j] = *reinterpret_cast<const bf16x8*>(Wt + brow[j] + kt * 32);
#pragma unroll
    for (int i = 0; i < 4; ++i)
#pragma unroll
      for (int j = 0; j < 4; ++j)
        acc[i][j] = __builtin_amdgcn_mfma_f32_16x16x32_bf16(a[i], b[j], acc[i][j], 0, 0, 0);
  }
#pragma unroll
  for (int i = 0; i < 4; ++i) {
#pragma unroll
    for (int r = 0; r < 4; ++r) {
      int row = m0 + i * 16 + lk * 4 + r;
      if (row >= M) continue;
#pragma unroll
      for (int j = 0; j < 4; ++j) {
        int col = n0 + j * 16 + lr;
        float v = acc[i][j][r] + bias[col];
        if constexpr (sizeof(OutT) == 2)
          Y[(size_t)row * N + col] = __float2bfloat16(v);
        else
          Y[(size_t)row * N + col] = v;
      }
    }
  }
}

// ---------------- init segment max + den ----------------
__global__ void init_md(unsigned* __restrict__ m, float* __restrict__ den, int n) {
  int i = blockIdx.x * blockDim.x + threadIdx.x;
  if (i < n) { m[i] = 0x007FFFFFu; den[i] = 0.f; }  // fenc(-inf)
}

// ---------------- edge scores + segment max (bf16 xl/xr) ----------------
__global__ __launch_bounds__(256) void edge_scores(
    const __hip_bfloat16* __restrict__ xl, const __hip_bfloat16* __restrict__ xr,
    const int* __restrict__ src_arr, const int* __restrict__ dst_arr,
    int E_main, int n_total, const float* __restrict__ att,
    float* __restrict__ e_out, unsigned* __restrict__ m_ord) {
  int w = blockIdx.x * 4 + (threadIdx.x >> 6);
  int lane = threadIdx.x & 63;
  if (w >= n_total) return;
  int s, d;
  if (w < E_main) { s = src_arr[w]; d = dst_arr[w]; }
  else { s = d = w - E_main; }  // self loop
  const __hip_bfloat16* pl = xl + (size_t)s * DDIM;
  const __hip_bfloat16* pr = xr + (size_t)d * DDIM;
  float v[4];
#pragma unroll
  for (int h = 0; h < 4; ++h) {
    float t = __bfloat162float(pl[h * 64 + lane]) + __bfloat162float(pr[h * 64 + lane]);
    t = (t >= 0.f) ? t : 0.2f * t;  // leaky_relu 0.2
    v[h] = t * att[h * 64 + lane];
  }
#pragma unroll
  for (int off = 32; off; off >>= 1) {
    v[0] += __shfl_xor(v[0], off);
    v[1] += __shfl_xor(v[1], off);
    v[2] += __shfl_xor(v[2], off);
    v[3] += __shfl_xor(v[3], off);
  }
  if (lane == 0) {
#pragma unroll
    for (int h = 0; h < 4; ++h) {
      e_out[(size_t)w * 4 + h] = v[h];
      atomicMax(&m_ord[(size_t)d * 4 + h], fenc(v[h]));
    }
  }
}

// ---------------- exp(e - m[dst]) in place + denominator ----------------
__global__ __launch_bounds__(256) void edge_softmax_den(
    float* __restrict__ e_inout, const int* __restrict__ dst_arr,
    int E_main, int n_total, const unsigned* __restrict__ m_ord,
    float* __restrict__ den) {
  int i = blockIdx.x * blockDim.x + threadIdx.x;
  if (i >= n_total * 4) return;
  int w = i >> 2, h = i & 3;
  int d = (w < E_main) ? dst_arr[w] : (w - E_main);
  float m = fdec(m_ord[(size_t)d * 4 + h]);
  float ex = expf(e_inout[i] - m);
  e_inout[i] = ex;
  atomicAdd(&den[(size_t)d * 4 + h], ex);
}

// ---------------- aggregate (bf16 xl) ----------------
__global__ __launch_bounds__(256) void edge_aggregate(
    const __hip_bfloat16* __restrict__ xl, const float* __restrict__ ex,
    const float* __restrict__ den, const int* __restrict__ src_arr,
    const int* __restrict__ dst_arr, int E_main, int n_total,
    float* __restrict__ acc) {
  int w = blockIdx.x * 4 + (threadIdx.x >> 6);
  int lane = threadIdx.x & 63;
  if (w >= n_total) return;
  int s, d;
  if (w < E_main) { s = src_arr[w]; d = dst_arr[w]; }
  else { s = d = w - E_main; }
  float a[4];
#pragma unroll
  for (int h = 0; h < 4; ++h)
    a[h] = ex[(size_t)w * 4 + h] / (den[(size_t)d * 4 + h] + 1e-16f);
  const __hip_bfloat16* pl = xl + (size_t)s * DDIM;
  float v = a[0] * __bfloat162float(pl[lane]) +
            a[1] * __bfloat162float(pl[64 + lane]) +
            a[2] * __bfloat162float(pl[128 + lane]) +
            a[3] * __bfloat162float(pl[192 + lane]);
  atomicAdd(&acc[(size_t)d * 64 + lane], 0.25f * v);
}

// ---------------- finalize: elu + residual + LN + threefry dropout ----------------
__global__ __launch_bounds__(256) void finalize(
    const float* __restrict__ acc, float* __restrict__ out,
    const float* __restrict__ bA, const float* __restrict__ bB, float scale,
    const float* __restrict__ g, const float* __restrict__ beta,
    int Nn, unsigned key0, unsigned key1) {
  int w = blockIdx.x * 4 + (threadIdx.x >> 6);
  int lane = threadIdx.x & 63;
  if (w >= Nn) return;
  unsigned idx = (unsigned)w * 64u + (unsigned)lane;
  float bias = bA[lane] + (bB ? bB[lane] : 0.f);
  float pre = scale * (acc[idx] + bias);
  pre = (pre > 0.f) ? pre : expm1f(pre);  // elu
  pre += out[idx];                        // + proj (bias already added)
  float mu = pre;
#pragma unroll
  for (int off = 32; off; off >>= 1) mu += __shfl_xor(mu, off);
  mu *= (1.0f / 64.0f);
  float dv = pre - mu;
  float var = dv * dv;
#pragma unroll
  for (int off = 32; off; off >>= 1) var += __shfl_xor(var, off);
  var *= (1.0f / 64.0f);
  float y = dv * rsqrtf(var + 1e-5f) * g[lane] + beta[lane];
  unsigned o0, o1;
  tf2x32(key0, key1, 0u, idx, o0, o1);
  unsigned bits = o0 ^ o1;
  float u = __uint_as_float((bits >> 9) | 0x3f800000u) - 1.0f;
  y = (u < 0.8f) ? y / 0.8f : 0.0f;
  out[idx] = y;
}

// ---------------- launch ----------------
extern "C" void kernel_launch(void* const* d_in, const int* in_sizes, int n_in,
                              void* d_out, int out_size, void* d_ws, size_t ws_size,
                              hipStream_t stream) {
  const float* x_met = (const float*)d_in[0];
  const float* x_rxn = (const float*)d_in[1];
  const int* sub_src = (const int*)d_in[2];
  const int* sub_dst = (const int*)d_in[3];
  const int* prod_src = (const int*)d_in[4];
  const int* prod_dst = (const int*)d_in[5];
  const int* shr_src = (const int*)d_in[6];
  const int* shr_dst = (const int*)d_in[7];
  const float* Wl_sub = (const float*)d_in[8];
  const float* bl_sub = (const float*)d_in[9];
  const float* Wr_sub = (const float*)d_in[10];
  const float* br_sub = (const float*)d_in[11];
  const float* att_sub = (const float*)d_in[12];
  const float* b_sub = (const float*)d_in[13];
  const float* Wl_prod = (const float*)d_in[14];
  const float* bl_prod = (const float*)d_in[15];
  const float* Wr_prod = (const float*)d_in[16];
  const float* br_prod = (const float*)d_in[17];
  const float* att_prod = (const float*)d_in[18];
  const float* b_prod = (const float*)d_in[19];
  const float* Wl_shr = (const float*)d_in[20];
  const float* bl_shr = (const float*)d_in[21];
  const float* Wr_shr = (const float*)d_in[22];
  const float* br_shr = (const float*)d_in[23];
  const float* att_shr = (const float*)d_in[24];
  const float* b_shr = (const float*)d_in[25];
  const float* W_proj_rxn = (const float*)d_in[26];
  const float* b_proj_rxn = (const float*)d_in[27];
  const float* W_proj_met = (const float*)d_in[28];
  const float* b_proj_met = (const float*)d_in[29];
  const float* ln_rxn_g = (const float*)d_in[30];
  const float* ln_rxn_b = (const float*)d_in[31];
  const float* ln_met_g = (const float*)d_in[32];
  const float* ln_met_b = (const float*)d_in[33];

  const int E = in_sizes[2];      // 250000
  const int E_shr = E + NRXN;     // with self loops

  // workspace carve (bytes)
  char* p = (char*)d_ws;
  __hip_bfloat16* xmb = (__hip_bfloat16*)p; p += (size_t)NMET * DDIM * 2;
  __hip_bfloat16* xrb = (__hip_bfloat16*)p; p += (size_t)NRXN * DDIM * 2;
  __hip_bfloat16* wt[8];
  for (int i = 0; i < 6; ++i) { wt[i] = (__hip_bfloat16*)p; p += 256 * 256 * 2; }
  for (int i = 6; i < 8; ++i) { wt[i] = (__hip_bfloat16*)p; p += 64 * 256 * 2; }
  __hip_bfloat16* xl_bf = (__hip_bfloat16*)p; p += (size_t)NRXN * DDIM * 2;
  __hip_bfloat16* xr_bf = (__hip_bfloat16*)p; p += (size_t)NRXN * DDIM * 2;
  float* e_buf = (float*)p; p += (size_t)E_shr * 4 * 4;
  unsigned* m_buf = (unsigned*)p; p += (size_t)NRXN * 4 * 4;
  float* den_buf = (float*)p; p += (size_t)NRXN * 4 * 4;
  float* acc_rxn = (float*)p; p += (size_t)NRXN * CDIM * 4;
  float* acc_met = (float*)p; p += (size_t)NMET * CDIM * 4;

  float* out_rxn = (float*)d_out;
  float* out_met = out_rxn + (size_t)NRXN * CDIM;

  // host-side threefry split (partitionable): subkey i = tf(key, (0, i))
  unsigned k1_0, k1_1, k2_0, k2_1;
  tf2x32(0u, 1u, 0u, 0u, k1_0, k1_1);
  tf2x32(0u, 1u, 0u, 1u, k2_0, k2_1);

  dim3 blk(256);

  // prep: convert + transpose
  cvt_bf16<<<(NMET * DDIM / 8 + 255) / 256, blk, 0, stream>>>(x_met, xmb, NMET * DDIM);
  cvt_bf16<<<(NRXN * DDIM / 8 + 255) / 256, blk, 0, stream>>>(x_rxn, xrb, NRXN * DDIM);
  wtrans<<<dim3(64, 8), blk, 0, stream>>>(
      Wl_sub, Wr_sub, Wl_shr, Wr_shr, Wl_prod, Wr_prod, W_proj_rxn, W_proj_met,
      wt[0], wt[1], wt[2], wt[3], wt[4], wt[5], wt[6], wt[7]);

  // zero accumulators (contiguous)
  hipMemsetAsync(acc_rxn, 0, (size_t)(NRXN + NMET) * CDIM * sizeof(float), stream);

  const int MT_MET = (NMET + 63) / 64, MT_RXN = (NRXN + 63) / 64;

  // projection GEMMs into d_out (scratch until finalize)
  gemm_mfma<float><<<(MT_RXN + 3) / 4, blk, 0, stream>>>(xrb, wt[6], b_proj_rxn, out_rxn, NRXN, CDIM);
  gemm_mfma<float><<<(MT_MET + 3) / 4, blk, 0, stream>>>(xmb, wt[7], b_proj_met, out_met, NMET, CDIM);

  // ---------- relation: substrate (met -> rxn) ----------
  gemm_mfma<__hip_bfloat16><<<(MT_MET * 4 + 3) / 4, blk, 0, stream>>>(xmb, wt[0], bl_sub, xl_bf, NMET, DDIM);
  gemm_mfma<__hip_bfloat16><<<(MT_RXN * 4 + 3) / 4, blk, 0, stream>>>(xrb, wt[1], br_sub, xr_bf, NRXN, DDIM);
  init_md<<<(NRXN * 4 + 255) / 256, blk, 0, stream>>>(m_buf, den_buf, NRXN * 4);
  edge_scores<<<(E + 3) / 4, blk, 0, stream>>>(
      xl_bf, xr_bf, sub_src, sub_dst, E, E, att_sub, e_buf, m_buf);
  edge_softmax_den<<<(E * 4 + 255) / 256, blk, 0, stream>>>(
      e_buf, sub_dst, E, E, m_buf, den_buf);
  edge_aggregate<<<(E + 3) / 4, blk, 0, stream>>>(
      xl_bf, e_buf, den_buf, sub_src, sub_dst, E, E, acc_rxn);

  // ---------- relation: shared_metabolite (rxn -> rxn, +self loops) ----------
  gemm_mfma<__hip_bfloat16><<<(MT_RXN * 4 + 3) / 4, blk, 0, stream>>>(xrb, wt[2], bl_shr, xl_bf, NRXN, DDIM);
  gemm_mfma<__hip_bfloat16><<<(MT_RXN * 4 + 3) / 4, blk, 0, stream>>>(xrb, wt[3], br_shr, xr_bf, NRXN, DDIM);
  init_md<<<(NRXN * 4 + 255) / 256, blk, 0, stream>>>(m_buf, den_buf, NRXN * 4);
  edge_scores<<<(E_shr + 3) / 4, blk, 0, stream>>>(
      xl_bf, xr_bf, shr_src, shr_dst, E, E_shr, att_shr, e_buf, m_buf);
  edge_softmax_den<<<(E_shr * 4 + 255) / 256, blk, 0, stream>>>(
      e_buf, shr_dst, E, E_shr, m_buf, den_buf);
  edge_aggregate<<<(E_shr + 3) / 4, blk, 0, stream>>>(
      xl_bf, e_buf, den_buf, shr_src, shr_dst, E, E_shr, acc_rxn);

  // ---------- relation: product (rxn -> met) ----------
  gemm_mfma<__hip_bfloat16><<<(MT_RXN * 4 + 3) / 4, blk, 0, stream>>>(xrb, wt[4], bl_prod, xl_bf, NRXN, DDIM);
  gemm_mfma<__hip_bfloat16><<<(MT_MET * 4 + 3) / 4, blk, 0, stream>>>(xmb, wt[5], br_prod, xr_bf, NMET, DDIM);
  init_md<<<(NMET * 4 + 255) / 256, blk, 0, stream>>>(m_buf, den_buf, NMET * 4);
  edge_scores<<<(E + 3) / 4, blk, 0, stream>>>(
      xl_bf, xr_bf, prod_src, prod_dst, E, E, att_prod, e_buf, m_buf);
  edge_softmax_den<<<(E * 4 + 255) / 256, blk, 0, stream>>>(
      e_buf, prod_dst, E, E, m_buf, den_buf);
  edge_aggregate<<<(E + 3) / 4, blk, 0, stream>>>(
      xl_bf, e_buf, den_buf, prod_src, prod_dst, E, E, acc_met);

  // ---------- finalize ----------
  finalize<<<(NRXN + 3) / 4, blk, 0, stream>>>(
      acc_rxn, out_rxn, b_sub, b_shr, 0.5f, ln_rxn_g, ln_rxn_b,
      NRXN, k1_0, k1_1);
  finalize<<<(NMET + 3) / 4, blk, 0, stream>>>(
      acc_met, out_met, b_prod, nullptr, 1.0f, ln_met_g, ln_met_b,
      NMET, k2_0, k2_1);
}

// Round 4
// 629.815 us; speedup vs baseline: 1.4873x; 1.0776x over previous
//
#include <hip/hip_runtime.h>
#include <hip/hip_bf16.h>
#include <stdint.h>

#define NMET 20000
#define NRXN 40000
#define DDIM 256
#define CDIM 64

typedef __attribute__((ext_vector_type(8))) short bf16x8;
typedef __attribute__((ext_vector_type(4))) float f32x4;

// ---------------- threefry2x32 (exact JAX semantics) ----------------
__host__ __device__ inline void tf2x32(unsigned k0, unsigned k1,
                                       unsigned x0, unsigned x1,
                                       unsigned &o0, unsigned &o1) {
  unsigned ks2 = k0 ^ k1 ^ 0x1BD11BDAu;
#define TFR(r) { x0 += x1; x1 = (x1 << r) | (x1 >> (32 - r)); x1 ^= x0; }
  x0 += k0; x1 += k1;
  TFR(13) TFR(15) TFR(26) TFR(6)
  x0 += k1; x1 += ks2 + 1u;
  TFR(17) TFR(29) TFR(16) TFR(24)
  x0 += ks2; x1 += k0 + 2u;
  TFR(13) TFR(15) TFR(26) TFR(6)
  x0 += k0; x1 += k1 + 3u;
  TFR(17) TFR(29) TFR(16) TFR(24)
  x0 += k1; x1 += ks2 + 4u;
  TFR(13) TFR(15) TFR(26) TFR(6)
  x0 += ks2; x1 += k0 + 5u;
#undef TFR
  o0 = x0; o1 = x1;
}

__device__ inline unsigned fenc(float f) {
  unsigned b = __float_as_uint(f);
  return (b & 0x80000000u) ? ~b : (b | 0x80000000u);
}
__device__ inline float fdec(unsigned u) {
  unsigned b = (u & 0x80000000u) ? (u & 0x7FFFFFFFu) : ~u;
  return __uint_as_float(b);
}

__device__ inline unsigned short f2bbits(float f) {
  __hip_bfloat16 h = __float2bfloat16(f);
  return *reinterpret_cast<unsigned short*>(&h);
}
__device__ inline float b2f(unsigned short u) {
  unsigned v = (unsigned)u << 16;
  return __uint_as_float(v);
}

// ---------------- fp32 -> bf16 convert (vectorized) ----------------
__global__ __launch_bounds__(256) void cvt_bf16(
    const float* __restrict__ in, __hip_bfloat16* __restrict__ out, int n) {
  int i = (blockIdx.x * 256 + threadIdx.x) * 8;
  if (i >= n) return;
  float4 a = *reinterpret_cast<const float4*>(in + i);
  float4 b = *reinterpret_cast<const float4*>(in + i + 4);
  bf16x8 o;
  o[0] = (short)f2bbits(a.x); o[1] = (short)f2bbits(a.y);
  o[2] = (short)f2bbits(a.z); o[3] = (short)f2bbits(a.w);
  o[4] = (short)f2bbits(b.x); o[5] = (short)f2bbits(b.y);
  o[6] = (short)f2bbits(b.z); o[7] = (short)f2bbits(b.w);
  *reinterpret_cast<bf16x8*>(out + i) = o;
}

// ---------------- W[k][n] -> Wt[n][k] bf16, 8 matrices fused ----------------
__global__ __launch_bounds__(256) void wtrans(
    const float* w0, const float* w1, const float* w2, const float* w3,
    const float* w4, const float* w5, const float* w6, const float* w7,
    __hip_bfloat16* o0, __hip_bfloat16* o1, __hip_bfloat16* o2, __hip_bfloat16* o3,
    __hip_bfloat16* o4, __hip_bfloat16* o5, __hip_bfloat16* o6, __hip_bfloat16* o7) {
  int z = blockIdx.y;
  const float* w; __hip_bfloat16* o; int Ncols;
  switch (z) {
    case 0: w = w0; o = o0; Ncols = 256; break;
    case 1: w = w1; o = o1; Ncols = 256; break;
    case 2: w = w2; o = o2; Ncols = 256; break;
    case 3: w = w3; o = o3; Ncols = 256; break;
    case 4: w = w4; o = o4; Ncols = 256; break;
    case 5: w = w5; o = o5; Ncols = 256; break;
    case 6: w = w6; o = o6; Ncols = 64; break;
    default: w = w7; o = o7; Ncols = 64; break;
  }
  int ntile = Ncols / 32;
  int t = blockIdx.x;
  if (t >= ntile * 8) return;  // K=256 -> 8 k-tiles
  int tn = t % ntile, tk = t / ntile;
  __shared__ float ts[32][33];
  int tx = threadIdx.x & 31, ty = threadIdx.x >> 5;
#pragma unroll
  for (int r = ty; r < 32; r += 8)
    ts[r][tx] = w[(size_t)(tk * 32 + r) * Ncols + tn * 32 + tx];
  __syncthreads();
#pragma unroll
  for (int r = ty; r < 32; r += 8)
    o[(size_t)(tn * 32 + r) * 256 + tk * 32 + tx] = __float2bfloat16(ts[tx][r]);
}

// ---------------- MFMA GEMM: Y[M,N] = Xb[M,256] @ Wt[N,256]^T + bias ----------------
template <typename OutT>
__global__ __launch_bounds__(256) void gemm_mfma(
    const __hip_bfloat16* __restrict__ Xb, const __hip_bfloat16* __restrict__ Wt,
    const float* __restrict__ bias, OutT* __restrict__ Y, int M, int N) {
  int wave = threadIdx.x >> 6;
  int lane = threadIdx.x & 63;
  int nt = N >> 6;
  int mt = (M + 63) >> 6;
  int tile = blockIdx.x * 4 + wave;
  if (tile >= mt * nt) return;
  int m0 = (tile / nt) * 64, n0 = (tile % nt) * 64;
  int lr = lane & 15, lk = lane >> 4;

  size_t arow[4], brow[4];
#pragma unroll
  for (int i = 0; i < 4; ++i) {
    int r = m0 + i * 16 + lr;
    if (r > M - 1) r = M - 1;
    arow[i] = (size_t)r * DDIM + lk * 8;
  }
#pragma unroll
  for (int j = 0; j < 4; ++j)
    brow[j] = (size_t)(n0 + j * 16 + lr) * DDIM + lk * 8;

  f32x4 acc[4][4] = {};
#pragma unroll
  for (int kt = 0; kt < 8; ++kt) {
    bf16x8 a[4], b[4];
#pragma unroll
    for (int i = 0; i < 4; ++i)
      a[i] = *reinterpret_cast<const bf16x8*>(Xb + arow[i] + kt * 32);
#pragma unroll
    for (int j = 0; j < 4; ++j)
      b[j] = *reinterpret_cast<const bf16x8*>(Wt + brow[j] + kt * 32);
#pragma unroll
    for (int i = 0; i < 4; ++i)
#pragma unroll
      for (int j = 0; j < 4; ++j)
        acc[i][j] = __builtin_amdgcn_mfma_f32_16x16x32_bf16(a[i], b[j], acc[i][j], 0, 0, 0);
  }
#pragma unroll
  for (int i = 0; i < 4; ++i) {
#pragma unroll
    for (int r = 0; r < 4; ++r) {
      int row = m0 + i * 16 + lk * 4 + r;
      if (row >= M) continue;
#pragma unroll
      for (int j = 0; j < 4; ++j) {
        int col = n0 + j * 16 + lr;
        float v = acc[i][j][r] + bias[col];
        if constexpr (sizeof(OutT) == 2)
          Y[(size_t)row * N + col] = __float2bfloat16(v);
        else
          Y[(size_t)row * N + col] = v;
      }
    }
  }
}

// ---------------- init segment max + den ----------------
__global__ void init_md(unsigned* __restrict__ m, float* __restrict__ den, int n) {
  int i = blockIdx.x * blockDim.x + threadIdx.x;
  if (i < n) { m[i] = 0x007FFFFFu; den[i] = 0.f; }  // fenc(-inf)
}

// ---------------- edge scores + segment max (vectorized, 16-lane-group reduce) ----------------
// lane l holds flat channels [4l,4l+3] = head l>>4, channels 4*(l&15)..+3
__global__ __launch_bounds__(256) void edge_scores(
    const __hip_bfloat16* __restrict__ xl, const __hip_bfloat16* __restrict__ xr,
    const int* __restrict__ src_arr, const int* __restrict__ dst_arr,
    int E_main, int n_total, const float* __restrict__ att,
    float* __restrict__ e_out, unsigned* __restrict__ m_ord) {
  int w = blockIdx.x * 4 + (threadIdx.x >> 6);
  int lane = threadIdx.x & 63;
  if (w >= n_total) return;
  int s, d;
  if (w < E_main) { s = src_arr[w]; d = dst_arr[w]; }
  else { s = d = w - E_main; }  // self loop
  ushort4 ua = *reinterpret_cast<const ushort4*>(xl + (size_t)s * DDIM + 4 * lane);
  ushort4 ub = *reinterpret_cast<const ushort4*>(xr + (size_t)d * DDIM + 4 * lane);
  float4 at = *reinterpret_cast<const float4*>(att + 4 * lane);
  float t0 = b2f(ua.x) + b2f(ub.x); t0 = (t0 >= 0.f) ? t0 : 0.2f * t0;
  float t1 = b2f(ua.y) + b2f(ub.y); t1 = (t1 >= 0.f) ? t1 : 0.2f * t1;
  float t2 = b2f(ua.z) + b2f(ub.z); t2 = (t2 >= 0.f) ? t2 : 0.2f * t2;
  float t3 = b2f(ua.w) + b2f(ub.w); t3 = (t3 >= 0.f) ? t3 : 0.2f * t3;
  float p = t0 * at.x + t1 * at.y + t2 * at.z + t3 * at.w;
  p += __shfl_xor(p, 1);
  p += __shfl_xor(p, 2);
  p += __shfl_xor(p, 4);
  p += __shfl_xor(p, 8);
  if ((lane & 15) == 0) {
    int h = lane >> 4;
    e_out[(size_t)w * 4 + h] = p;
    atomicMax(&m_ord[(size_t)d * 4 + h], fenc(p));
  }
}

// ---------------- exp(e - m[dst]) in place + denominator ----------------
__global__ __launch_bounds__(256) void edge_softmax_den(
    float* __restrict__ e_inout, const int* __restrict__ dst_arr,
    int E_main, int n_total, const unsigned* __restrict__ m_ord,
    float* __restrict__ den) {
  int i = blockIdx.x * blockDim.x + threadIdx.x;
  if (i >= n_total * 4) return;
  int w = i >> 2, h = i & 3;
  int d = (w < E_main) ? dst_arr[w] : (w - E_main);
  float m = fdec(m_ord[(size_t)d * 4 + h]);
  float ex = expf(e_inout[i] - m);
  e_inout[i] = ex;
  atomicAdd(&den[(size_t)d * 4 + h], ex);
}

// ---------------- aggregate (vectorized; butterfly + redistribute; coalesced atomic) ----------------
__global__ __launch_bounds__(256) void edge_aggregate(
    const __hip_bfloat16* __restrict__ xl, const float* __restrict__ ex,
    const float* __restrict__ den, const int* __restrict__ src_arr,
    const int* __restrict__ dst_arr, int E_main, int n_total,
    float* __restrict__ acc) {
  int w = blockIdx.x * 4 + (threadIdx.x >> 6);
  int lane = threadIdx.x & 63;
  if (w >= n_total) return;
  int s, d;
  if (w < E_main) { s = src_arr[w]; d = dst_arr[w]; }
  else { s = d = w - E_main; }
  int h = lane >> 4;
  float alpha = ex[(size_t)w * 4 + h] / (den[(size_t)d * 4 + h] + 1e-16f);
  ushort4 ua = *reinterpret_cast<const ushort4*>(xl + (size_t)s * DDIM + 4 * lane);
  float p0 = alpha * b2f(ua.x);
  float p1 = alpha * b2f(ua.y);
  float p2 = alpha * b2f(ua.z);
  float p3 = alpha * b2f(ua.w);
  // sum the 4 head groups (lanes l, l+16, l+32, l+48)
  p0 += __shfl_xor(p0, 16); p0 += __shfl_xor(p0, 32);
  p1 += __shfl_xor(p1, 16); p1 += __shfl_xor(p1, 32);
  p2 += __shfl_xor(p2, 16); p2 += __shfl_xor(p2, 32);
  p3 += __shfl_xor(p3, 16); p3 += __shfl_xor(p3, 32);
  // redistribute: lane m wants channel m = value (m&3) from lane (m>>2)
  int srcl = lane >> 2;
  float v0 = __shfl(p0, srcl);
  float v1 = __shfl(p1, srcl);
  float v2 = __shfl(p2, srcl);
  float v3 = __shfl(p3, srcl);
  float val = (lane & 2) ? ((lane & 1) ? v3 : v2) : ((lane & 1) ? v1 : v0);
  atomicAdd(&acc[(size_t)d * 64 + lane], 0.25f * val);
}

// ---------------- finalize: elu + residual + LN + threefry dropout ----------------
__global__ __launch_bounds__(256) void finalize(
    const float* __restrict__ acc, float* __restrict__ out,
    const float* __restrict__ bA, const float* __restrict__ bB, float scale,
    const float* __restrict__ g, const float* __restrict__ beta,
    int Nn, unsigned key0, unsigned key1) {
  int w = blockIdx.x * 4 + (threadIdx.x >> 6);
  int lane = threadIdx.x & 63;
  if (w >= Nn) return;
  unsigned idx = (unsigned)w * 64u + (unsigned)lane;
  float bias = bA[lane] + (bB ? bB[lane] : 0.f);
  float pre = scale * (acc[idx] + bias);
  pre = (pre > 0.f) ? pre : expm1f(pre);  // elu
  pre += out[idx];                        // + proj (bias already added)
  float mu = pre;
#pragma unroll
  for (int off = 32; off; off >>= 1) mu += __shfl_xor(mu, off);
  mu *= (1.0f / 64.0f);
  float dv = pre - mu;
  float var = dv * dv;
#pragma unroll
  for (int off = 32; off; off >>= 1) var += __shfl_xor(var, off);
  var *= (1.0f / 64.0f);
  float y = dv * rsqrtf(var + 1e-5f) * g[lane] + beta[lane];
  unsigned o0, o1;
  tf2x32(key0, key1, 0u, idx, o0, o1);
  unsigned bits = o0 ^ o1;
  float u = __uint_as_float((bits >> 9) | 0x3f800000u) - 1.0f;
  y = (u < 0.8f) ? y / 0.8f : 0.0f;
  out[idx] = y;
}

// ---------------- launch ----------------
extern "C" void kernel_launch(void* const* d_in, const int* in_sizes, int n_in,
                              void* d_out, int out_size, void* d_ws, size_t ws_size,
                              hipStream_t stream) {
  const float* x_met = (const float*)d_in[0];
  const float* x_rxn = (const float*)d_in[1];
  const int* sub_src = (const int*)d_in[2];
  const int* sub_dst = (const int*)d_in[3];
  const int* prod_src = (const int*)d_in[4];
  const int* prod_dst = (const int*)d_in[5];
  const int* shr_src = (const int*)d_in[6];
  const int* shr_dst = (const int*)d_in[7];
  const float* Wl_sub = (const float*)d_in[8];
  const float* bl_sub = (const float*)d_in[9];
  const float* Wr_sub = (const float*)d_in[10];
  const float* br_sub = (const float*)d_in[11];
  const float* att_sub = (const float*)d_in[12];
  const float* b_sub = (const float*)d_in[13];
  const float* Wl_prod = (const float*)d_in[14];
  const float* bl_prod = (const float*)d_in[15];
  const float* Wr_prod = (const float*)d_in[16];
  const float* br_prod = (const float*)d_in[17];
  const float* att_prod = (const float*)d_in[18];
  const float* b_prod = (const float*)d_in[19];
  const float* Wl_shr = (const float*)d_in[20];
  const float* bl_shr = (const float*)d_in[21];
  const float* Wr_shr = (const float*)d_in[22];
  const float* br_shr = (const float*)d_in[23];
  const float* att_shr = (const float*)d_in[24];
  const float* b_shr = (const float*)d_in[25];
  const float* W_proj_rxn = (const float*)d_in[26];
  const float* b_proj_rxn = (const float*)d_in[27];
  const float* W_proj_met = (const float*)d_in[28];
  const float* b_proj_met = (const float*)d_in[29];
  const float* ln_rxn_g = (const float*)d_in[30];
  const float* ln_rxn_b = (const float*)d_in[31];
  const float* ln_met_g = (const float*)d_in[32];
  const float* ln_met_b = (const float*)d_in[33];

  const int E = in_sizes[2];      // 250000
  const int E_shr = E + NRXN;     // with self loops

  // workspace carve (bytes)
  char* p = (char*)d_ws;
  __hip_bfloat16* xmb = (__hip_bfloat16*)p; p += (size_t)NMET * DDIM * 2;
  __hip_bfloat16* xrb = (__hip_bfloat16*)p; p += (size_t)NRXN * DDIM * 2;
  __hip_bfloat16* wt[8];
  for (int i = 0; i < 6; ++i) { wt[i] = (__hip_bfloat16*)p; p += 256 * 256 * 2; }
  for (int i = 6; i < 8; ++i) { wt[i] = (__hip_bfloat16*)p; p += 64 * 256 * 2; }
  __hip_bfloat16* xl_bf = (__hip_bfloat16*)p; p += (size_t)NRXN * DDIM * 2;
  __hip_bfloat16* xr_bf = (__hip_bfloat16*)p; p += (size_t)NRXN * DDIM * 2;
  float* e_buf = (float*)p; p += (size_t)E_shr * 4 * 4;
  unsigned* m_buf = (unsigned*)p; p += (size_t)NRXN * 4 * 4;
  float* den_buf = (float*)p; p += (size_t)NRXN * 4 * 4;
  float* acc_rxn = (float*)p; p += (size_t)NRXN * CDIM * 4;
  float* acc_met = (float*)p; p += (size_t)NMET * CDIM * 4;

  float* out_rxn = (float*)d_out;
  float* out_met = out_rxn + (size_t)NRXN * CDIM;

  // host-side threefry split (partitionable): subkey i = tf(key, (0, i))
  unsigned k1_0, k1_1, k2_0, k2_1;
  tf2x32(0u, 1u, 0u, 0u, k1_0, k1_1);
  tf2x32(0u, 1u, 0u, 1u, k2_0, k2_1);

  dim3 blk(256);

  // prep: convert + transpose
  cvt_bf16<<<(NMET * DDIM / 8 + 255) / 256, blk, 0, stream>>>(x_met, xmb, NMET * DDIM);
  cvt_bf16<<<(NRXN * DDIM / 8 + 255) / 256, blk, 0, stream>>>(x_rxn, xrb, NRXN * DDIM);
  wtrans<<<dim3(64, 8), blk, 0, stream>>>(
      Wl_sub, Wr_sub, Wl_shr, Wr_shr, Wl_prod, Wr_prod, W_proj_rxn, W_proj_met,
      wt[0], wt[1], wt[2], wt[3], wt[4], wt[5], wt[6], wt[7]);

  // zero accumulators (contiguous)
  hipMemsetAsync(acc_rxn, 0, (size_t)(NRXN + NMET) * CDIM * sizeof(float), stream);

  const int MT_MET = (NMET + 63) / 64, MT_RXN = (NRXN + 63) / 64;

  // projection GEMMs into d_out (scratch until finalize)
  gemm_mfma<float><<<(MT_RXN + 3) / 4, blk, 0, stream>>>(xrb, wt[6], b_proj_rxn, out_rxn, NRXN, CDIM);
  gemm_mfma<float><<<(MT_MET + 3) / 4, blk, 0, stream>>>(xmb, wt[7], b_proj_met, out_met, NMET, CDIM);

  // ---------- relation: substrate (met -> rxn) ----------
  gemm_mfma<__hip_bfloat16><<<(MT_MET * 4 + 3) / 4, blk, 0, stream>>>(xmb, wt[0], bl_sub, xl_bf, NMET, DDIM);
  gemm_mfma<__hip_bfloat16><<<(MT_RXN * 4 + 3) / 4, blk, 0, stream>>>(xrb, wt[1], br_sub, xr_bf, NRXN, DDIM);
  init_md<<<(NRXN * 4 + 255) / 256, blk, 0, stream>>>(m_buf, den_buf, NRXN * 4);
  edge_scores<<<(E + 3) / 4, blk, 0, stream>>>(
      xl_bf, xr_bf, sub_src, sub_dst, E, E, att_sub, e_buf, m_buf);
  edge_softmax_den<<<(E * 4 + 255) / 256, blk, 0, stream>>>(
      e_buf, sub_dst, E, E, m_buf, den_buf);
  edge_aggregate<<<(E + 3) / 4, blk, 0, stream>>>(
      xl_bf, e_buf, den_buf, sub_src, sub_dst, E, E, acc_rxn);

  // ---------- relation: shared_metabolite (rxn -> rxn, +self loops) ----------
  gemm_mfma<__hip_bfloat16><<<(MT_RXN * 4 + 3) / 4, blk, 0, stream>>>(xrb, wt[2], bl_shr, xl_bf, NRXN, DDIM);
  gemm_mfma<__hip_bfloat16><<<(MT_RXN * 4 + 3) / 4, blk, 0, stream>>>(xrb, wt[3], br_shr, xr_bf, NRXN, DDIM);
  init_md<<<(NRXN * 4 + 255) / 256, blk, 0, stream>>>(m_buf, den_buf, NRXN * 4);
  edge_scores<<<(E_shr + 3) / 4, blk, 0, stream>>>(
      xl_bf, xr_bf, shr_src, shr_dst, E, E_shr, att_shr, e_buf, m_buf);
  edge_softmax_den<<<(E_shr * 4 + 255) / 256, blk, 0, stream>>>(
      e_buf, shr_dst, E, E_shr, m_buf, den_buf);
  edge_aggregate<<<(E_shr + 3) / 4, blk, 0, stream>>>(
      xl_bf, e_buf, den_buf, shr_src, shr_dst, E, E_shr, acc_rxn);

  // ---------- relation: product (rxn -> met) ----------
  gemm_mfma<__hip_bfloat16><<<(MT_RXN * 4 + 3) / 4, blk, 0, stream>>>(xrb, wt[4], bl_prod, xl_bf, NRXN, DDIM);
  gemm_mfma<__hip_bfloat16><<<(MT_MET * 4 + 3) / 4, blk, 0, stream>>>(xmb, wt[5], br_prod, xr_bf, NMET, DDIM);
  init_md<<<(NMET * 4 + 255) / 256, blk, 0, stream>>>(m_buf, den_buf, NMET * 4);
  edge_scores<<<(E + 3) / 4, blk, 0, stream>>>(
      xl_bf, xr_bf, prod_src, prod_dst, E, E, att_prod, e_buf, m_buf);
  edge_softmax_den<<<(E * 4 + 255) / 256, blk, 0, stream>>>(
      e_buf, prod_dst, E, E, m_buf, den_buf);
  edge_aggregate<<<(E + 3) / 4, blk, 0, stream>>>(
      xl_bf, e_buf, den_buf, prod_src, prod_dst, E, E, acc_met);

  // ---------- finalize ----------
  finalize<<<(NRXN + 3) / 4, blk, 0, stream>>>(
      acc_rxn, out_rxn, b_sub, b_shr, 0.5f, ln_rxn_g, ln_rxn_b,
      NRXN, k1_0, k1_1);
  finalize<<<(NMET + 3) / 4, blk, 0, stream>>>(
      acc_met, out_met, b_prod, nullptr, 1.0f, ln_met_g, ln_met_b,
      NMET, k2_0, k2_1);
}

// Round 5
// 529.592 us; speedup vs baseline: 1.7688x; 1.1892x over previous
//
#include <hip/hip_runtime.h>
#include <hip/hip_bf16.h>
#include <stdint.h>

#define NMET 20000
#define NRXN 40000
#define DDIM 256
#define CDIM 64

typedef __attribute__((ext_vector_type(8))) short bf16x8;
typedef __attribute__((ext_vector_type(4))) float f32x4;

// ---------------- threefry2x32 (exact JAX semantics) ----------------
__host__ __device__ inline void tf2x32(unsigned k0, unsigned k1,
                                       unsigned x0, unsigned x1,
                                       unsigned &o0, unsigned &o1) {
  unsigned ks2 = k0 ^ k1 ^ 0x1BD11BDAu;
#define TFR(r) { x0 += x1; x1 = (x1 << r) | (x1 >> (32 - r)); x1 ^= x0; }
  x0 += k0; x1 += k1;
  TFR(13) TFR(15) TFR(26) TFR(6)
  x0 += k1; x1 += ks2 + 1u;
  TFR(17) TFR(29) TFR(16) TFR(24)
  x0 += ks2; x1 += k0 + 2u;
  TFR(13) TFR(15) TFR(26) TFR(6)
  x0 += k0; x1 += k1 + 3u;
  TFR(17) TFR(29) TFR(16) TFR(24)
  x0 += k1; x1 += ks2 + 4u;
  TFR(13) TFR(15) TFR(26) TFR(6)
  x0 += ks2; x1 += k0 + 5u;
#undef TFR
  o0 = x0; o1 = x1;
}

__device__ inline unsigned short f2bbits(float f) {
  __hip_bfloat16 h = __float2bfloat16(f);
  return *reinterpret_cast<unsigned short*>(&h);
}
__device__ inline float b2f(unsigned short u) {
  unsigned v = (unsigned)u << 16;
  return __uint_as_float(v);
}

// ---------------- fp32 -> bf16 convert (vectorized) ----------------
__global__ __launch_bounds__(256) void cvt_bf16(
    const float* __restrict__ in, __hip_bfloat16* __restrict__ out, int n) {
  int i = (blockIdx.x * 256 + threadIdx.x) * 8;
  if (i >= n) return;
  float4 a = *reinterpret_cast<const float4*>(in + i);
  float4 b = *reinterpret_cast<const float4*>(in + i + 4);
  bf16x8 o;
  o[0] = (short)f2bbits(a.x); o[1] = (short)f2bbits(a.y);
  o[2] = (short)f2bbits(a.z); o[3] = (short)f2bbits(a.w);
  o[4] = (short)f2bbits(b.x); o[5] = (short)f2bbits(b.y);
  o[6] = (short)f2bbits(b.z); o[7] = (short)f2bbits(b.w);
  *reinterpret_cast<bf16x8*>(out + i) = o;
}

// ---------------- W[k][n] -> Wt[n][k] bf16, 8 matrices fused ----------------
__global__ __launch_bounds__(256) void wtrans(
    const float* w0, const float* w1, const float* w2, const float* w3,
    const float* w4, const float* w5, const float* w6, const float* w7,
    __hip_bfloat16* o0, __hip_bfloat16* o1, __hip_bfloat16* o2, __hip_bfloat16* o3,
    __hip_bfloat16* o4, __hip_bfloat16* o5, __hip_bfloat16* o6, __hip_bfloat16* o7) {
  int z = blockIdx.y;
  const float* w; __hip_bfloat16* o; int Ncols;
  switch (z) {
    case 0: w = w0; o = o0; Ncols = 256; break;
    case 1: w = w1; o = o1; Ncols = 256; break;
    case 2: w = w2; o = o2; Ncols = 256; break;
    case 3: w = w3; o = o3; Ncols = 256; break;
    case 4: w = w4; o = o4; Ncols = 256; break;
    case 5: w = w5; o = o5; Ncols = 256; break;
    case 6: w = w6; o = o6; Ncols = 64; break;
    default: w = w7; o = o7; Ncols = 64; break;
  }
  int ntile = Ncols / 32;
  int t = blockIdx.x;
  if (t >= ntile * 8) return;  // K=256 -> 8 k-tiles
  int tn = t % ntile, tk = t / ntile;
  __shared__ float ts[32][33];
  int tx = threadIdx.x & 31, ty = threadIdx.x >> 5;
#pragma unroll
  for (int r = ty; r < 32; r += 8)
    ts[r][tx] = w[(size_t)(tk * 32 + r) * Ncols + tn * 32 + tx];
  __syncthreads();
#pragma unroll
  for (int r = ty; r < 32; r += 8)
    o[(size_t)(tn * 32 + r) * 256 + tk * 32 + tx] = __float2bfloat16(ts[tx][r]);
}

// ---------------- MFMA GEMM: Y[M,N] = Xb[M,256] @ Wt[N,256]^T + bias ----------------
template <typename OutT>
__global__ __launch_bounds__(256) void gemm_mfma(
    const __hip_bfloat16* __restrict__ Xb, const __hip_bfloat16* __restrict__ Wt,
    const float* __restrict__ bias, OutT* __restrict__ Y, int M, int N) {
  int wave = threadIdx.x >> 6;
  int lane = threadIdx.x & 63;
  int nt = N >> 6;
  int mt = (M + 63) >> 6;
  int tile = blockIdx.x * 4 + wave;
  if (tile >= mt * nt) return;
  int m0 = (tile / nt) * 64, n0 = (tile % nt) * 64;
  int lr = lane & 15, lk = lane >> 4;

  size_t arow[4], brow[4];
#pragma unroll
  for (int i = 0; i < 4; ++i) {
    int r = m0 + i * 16 + lr;
    if (r > M - 1) r = M - 1;
    arow[i] = (size_t)r * DDIM + lk * 8;
  }
#pragma unroll
  for (int j = 0; j < 4; ++j)
    brow[j] = (size_t)(n0 + j * 16 + lr) * DDIM + lk * 8;

  f32x4 acc[4][4] = {};
#pragma unroll
  for (int kt = 0; kt < 8; ++kt) {
    bf16x8 a[4], b[4];
#pragma unroll
    for (int i = 0; i < 4; ++i)
      a[i] = *reinterpret_cast<const bf16x8*>(Xb + arow[i] + kt * 32);
#pragma unroll
    for (int j = 0; j < 4; ++j)
      b[j] = *reinterpret_cast<const bf16x8*>(Wt + brow[j] + kt * 32);
#pragma unroll
    for (int i = 0; i < 4; ++i)
#pragma unroll
      for (int j = 0; j < 4; ++j)
        acc[i][j] = __builtin_amdgcn_mfma_f32_16x16x32_bf16(a[i], b[j], acc[i][j], 0, 0, 0);
  }
#pragma unroll
  for (int i = 0; i < 4; ++i) {
#pragma unroll
    for (int r = 0; r < 4; ++r) {
      int row = m0 + i * 16 + lk * 4 + r;
      if (row >= M) continue;
#pragma unroll
      for (int j = 0; j < 4; ++j) {
        int col = n0 + j * 16 + lr;
        float v = acc[i][j][r] + bias[col];
        if constexpr (sizeof(OutT) == 2)
          Y[(size_t)row * N + col] = __float2bfloat16(v);
        else
          Y[(size_t)row * N + col] = v;
      }
    }
  }
}

// ---------------- CSR build: histogram over 3 relations ----------------
__global__ __launch_bounds__(256) void hist3(
    const int* __restrict__ d0, const int* __restrict__ d1, const int* __restrict__ d2,
    int E, int* __restrict__ c0, int* __restrict__ c1, int* __restrict__ c2) {
  int i = blockIdx.x * 256 + threadIdx.x;
  if (i >= E) return;
  int rel = blockIdx.y;
  if (rel == 0) atomicAdd(&c0[d0[i]], 1);
  else if (rel == 1) atomicAdd(&c1[d1[i]], 1);
  else atomicAdd(&c2[d2[i]], 1);
}

// ---------------- CSR build: exclusive scan (one block per relation) ----------------
__global__ __launch_bounds__(1024) void scan3(
    const int* __restrict__ c0, const int* __restrict__ c1, const int* __restrict__ c2,
    int* __restrict__ o0, int* __restrict__ o1, int* __restrict__ o2,
    int* __restrict__ u0, int* __restrict__ u1, int* __restrict__ u2,
    int n0, int n1, int n2) {
  int rel = blockIdx.x;
  const int* cnt = (rel == 0) ? c0 : (rel == 1) ? c1 : c2;
  int* off = (rel == 0) ? o0 : (rel == 1) ? o1 : o2;
  int* cur = (rel == 0) ? u0 : (rel == 1) ? u1 : u2;
  int n = (rel == 0) ? n0 : (rel == 1) ? n1 : n2;
  __shared__ int sums[1024];
  int t = threadIdx.x;
  int chunk = (n + 1023) / 1024;
  int lo = t * chunk; if (lo > n) lo = n;
  int hi = lo + chunk; if (hi > n) hi = n;
  int s = 0;
  for (int i = lo; i < hi; ++i) s += cnt[i];
  sums[t] = s;
  __syncthreads();
  for (int dstep = 1; dstep < 1024; dstep <<= 1) {
    int v = (t >= dstep) ? sums[t - dstep] : 0;
    __syncthreads();
    sums[t] += v;
    __syncthreads();
  }
  int run = (t == 0) ? 0 : sums[t - 1];
  for (int i = lo; i < hi; ++i) {
    off[i] = run; cur[i] = run;
    run += cnt[i];
  }
  if (t == 1023) off[n] = run;
}

// ---------------- CSR build: scatter source ids ----------------
__global__ __launch_bounds__(256) void scatter3(
    const int* __restrict__ s0, const int* __restrict__ d0,
    const int* __restrict__ s1, const int* __restrict__ d1,
    const int* __restrict__ s2, const int* __restrict__ d2,
    int E, int* __restrict__ u0, int* __restrict__ u1, int* __restrict__ u2,
    int* __restrict__ e0, int* __restrict__ e1, int* __restrict__ e2) {
  int i = blockIdx.x * 256 + threadIdx.x;
  if (i >= E) return;
  int rel = blockIdx.y;
  if (rel == 0)      { int pos = atomicAdd(&u0[d0[i]], 1); e0[pos] = s0[i]; }
  else if (rel == 1) { int pos = atomicAdd(&u1[d1[i]], 1); e1[pos] = s1[i]; }
  else               { int pos = atomicAdd(&u2[d2[i]], 1); e2[pos] = s2[i]; }
}

// ---------------- fused GATv2 per destination node (online softmax) ----------------
// wave per dst: lane l holds flat channels [4l,4l+3] = head l>>4
__global__ __launch_bounds__(256) void gat_node(
    const __hip_bfloat16* __restrict__ xl, const __hip_bfloat16* __restrict__ xr,
    const int* __restrict__ off, const int* __restrict__ srce,
    const float* __restrict__ att, float* __restrict__ accout,
    int n, int self_loop) {
  int d = blockIdx.x * 4 + (threadIdx.x >> 6);
  int lane = threadIdx.x & 63;
  if (d >= n) return;
  int beg = off[d], end = off[d + 1];
  int total = (end - beg) + self_loop;

  ushort4 ur = *reinterpret_cast<const ushort4*>(xr + (size_t)d * DDIM + 4 * lane);
  float r0 = b2f(ur.x), r1 = b2f(ur.y), r2 = b2f(ur.z), r3 = b2f(ur.w);
  float4 at = *reinterpret_cast<const float4*>(att + 4 * lane);

  float m = -INFINITY, den = 0.f;
  float a0 = 0.f, a1 = 0.f, a2 = 0.f, a3 = 0.f;
  for (int it = 0; it < total; ++it) {
    int s = (self_loop && it == 0) ? d : srce[beg + it - self_loop];
    ushort4 ux = *reinterpret_cast<const ushort4*>(xl + (size_t)s * DDIM + 4 * lane);
    float x0 = b2f(ux.x), x1 = b2f(ux.y), x2 = b2f(ux.z), x3 = b2f(ux.w);
    float t0 = x0 + r0; t0 = (t0 >= 0.f) ? t0 : 0.2f * t0;
    float t1 = x1 + r1; t1 = (t1 >= 0.f) ? t1 : 0.2f * t1;
    float t2 = x2 + r2; t2 = (t2 >= 0.f) ? t2 : 0.2f * t2;
    float t3 = x3 + r3; t3 = (t3 >= 0.f) ? t3 : 0.2f * t3;
    float p = t0 * at.x + t1 * at.y + t2 * at.z + t3 * at.w;
    p += __shfl_xor(p, 1);
    p += __shfl_xor(p, 2);
    p += __shfl_xor(p, 4);
    p += __shfl_xor(p, 8);
    float nm = fmaxf(m, p);
    float sc = __expf(m - nm);   // first iter: exp(-inf)=0
    float ex = __expf(p - nm);
    den = den * sc + ex;
    a0 = a0 * sc + ex * x0;
    a1 = a1 * sc + ex * x1;
    a2 = a2 * sc + ex * x2;
    a3 = a3 * sc + ex * x3;
    m = nm;
  }
  float inv = (den > 0.f) ? 1.0f / den : 0.f;
  float p0 = a0 * inv, p1 = a1 * inv, p2 = a2 * inv, p3 = a3 * inv;
  // mean over 4 heads: sum groups (lanes l, l+16, l+32, l+48), then redistribute
  p0 += __shfl_xor(p0, 16); p0 += __shfl_xor(p0, 32);
  p1 += __shfl_xor(p1, 16); p1 += __shfl_xor(p1, 32);
  p2 += __shfl_xor(p2, 16); p2 += __shfl_xor(p2, 32);
  p3 += __shfl_xor(p3, 16); p3 += __shfl_xor(p3, 32);
  int srcl = lane >> 2;
  float v0 = __shfl(p0, srcl);
  float v1 = __shfl(p1, srcl);
  float v2 = __shfl(p2, srcl);
  float v3 = __shfl(p3, srcl);
  float val = (lane & 2) ? ((lane & 1) ? v3 : v2) : ((lane & 1) ? v1 : v0);
  accout[(size_t)d * 64 + lane] = 0.25f * val;
}

// ---------------- finalize: elu + residual + LN + threefry dropout ----------------
__global__ __launch_bounds__(256) void finalize(
    const float* __restrict__ accA, const float* __restrict__ accB,
    float* __restrict__ out,
    const float* __restrict__ bA, const float* __restrict__ bB, float scale,
    const float* __restrict__ g, const float* __restrict__ beta,
    int Nn, unsigned key0, unsigned key1) {
  int w = blockIdx.x * 4 + (threadIdx.x >> 6);
  int lane = threadIdx.x & 63;
  if (w >= Nn) return;
  unsigned idx = (unsigned)w * 64u + (unsigned)lane;
  float bias = bA[lane] + (bB ? bB[lane] : 0.f);
  float agg = accA[idx] + (accB ? accB[idx] : 0.f);
  float pre = scale * (agg + bias);
  pre = (pre > 0.f) ? pre : expm1f(pre);  // elu
  pre += out[idx];                        // + proj (bias already added)
  float mu = pre;
#pragma unroll
  for (int off = 32; off; off >>= 1) mu += __shfl_xor(mu, off);
  mu *= (1.0f / 64.0f);
  float dv = pre - mu;
  float var = dv * dv;
#pragma unroll
  for (int off = 32; off; off >>= 1) var += __shfl_xor(var, off);
  var *= (1.0f / 64.0f);
  float y = dv * rsqrtf(var + 1e-5f) * g[lane] + beta[lane];
  unsigned o0, o1;
  tf2x32(key0, key1, 0u, idx, o0, o1);
  unsigned bits = o0 ^ o1;
  float u = __uint_as_float((bits >> 9) | 0x3f800000u) - 1.0f;
  y = (u < 0.8f) ? y / 0.8f : 0.0f;
  out[idx] = y;
}

// ---------------- launch ----------------
extern "C" void kernel_launch(void* const* d_in, const int* in_sizes, int n_in,
                              void* d_out, int out_size, void* d_ws, size_t ws_size,
                              hipStream_t stream) {
  const float* x_met = (const float*)d_in[0];
  const float* x_rxn = (const float*)d_in[1];
  const int* sub_src = (const int*)d_in[2];
  const int* sub_dst = (const int*)d_in[3];
  const int* prod_src = (const int*)d_in[4];
  const int* prod_dst = (const int*)d_in[5];
  const int* shr_src = (const int*)d_in[6];
  const int* shr_dst = (const int*)d_in[7];
  const float* Wl_sub = (const float*)d_in[8];
  const float* bl_sub = (const float*)d_in[9];
  const float* Wr_sub = (const float*)d_in[10];
  const float* br_sub = (const float*)d_in[11];
  const float* att_sub = (const float*)d_in[12];
  const float* b_sub = (const float*)d_in[13];
  const float* Wl_prod = (const float*)d_in[14];
  const float* bl_prod = (const float*)d_in[15];
  const float* Wr_prod = (const float*)d_in[16];
  const float* br_prod = (const float*)d_in[17];
  const float* att_prod = (const float*)d_in[18];
  const float* b_prod = (const float*)d_in[19];
  const float* Wl_shr = (const float*)d_in[20];
  const float* bl_shr = (const float*)d_in[21];
  const float* Wr_shr = (const float*)d_in[22];
  const float* br_shr = (const float*)d_in[23];
  const float* att_shr = (const float*)d_in[24];
  const float* b_shr = (const float*)d_in[25];
  const float* W_proj_rxn = (const float*)d_in[26];
  const float* b_proj_rxn = (const float*)d_in[27];
  const float* W_proj_met = (const float*)d_in[28];
  const float* b_proj_met = (const float*)d_in[29];
  const float* ln_rxn_g = (const float*)d_in[30];
  const float* ln_rxn_b = (const float*)d_in[31];
  const float* ln_met_g = (const float*)d_in[32];
  const float* ln_met_b = (const float*)d_in[33];

  const int E = in_sizes[2];  // 250000

  // workspace carve (bytes)
  char* p = (char*)d_ws;
  __hip_bfloat16* xmb = (__hip_bfloat16*)p; p += (size_t)NMET * DDIM * 2;
  __hip_bfloat16* xrb = (__hip_bfloat16*)p; p += (size_t)NRXN * DDIM * 2;
  __hip_bfloat16* wt[8];
  for (int i = 0; i < 6; ++i) { wt[i] = (__hip_bfloat16*)p; p += 256 * 256 * 2; }
  for (int i = 6; i < 8; ++i) { wt[i] = (__hip_bfloat16*)p; p += 64 * 256 * 2; }
  __hip_bfloat16* xl_bf = (__hip_bfloat16*)p; p += (size_t)NRXN * DDIM * 2;
  __hip_bfloat16* xr_bf = (__hip_bfloat16*)p; p += (size_t)NRXN * DDIM * 2;
  float* acc_sub = (float*)p; p += (size_t)NRXN * CDIM * 4;
  float* acc_shr = (float*)p; p += (size_t)NRXN * CDIM * 4;
  float* acc_met = (float*)p; p += (size_t)NMET * CDIM * 4;
  // CSR arrays
  int* cnt_sub = (int*)p; p += (size_t)NRXN * 4;
  int* cnt_shr = (int*)p; p += (size_t)NRXN * 4;
  int* cnt_prod = (int*)p; p += (size_t)NMET * 4;
  int* off_sub = (int*)p; p += (size_t)(NRXN + 1) * 4;
  int* off_shr = (int*)p; p += (size_t)(NRXN + 1) * 4;
  int* off_prod = (int*)p; p += (size_t)(NMET + 1) * 4;
  int* cur_sub = (int*)p; p += (size_t)NRXN * 4;
  int* cur_shr = (int*)p; p += (size_t)NRXN * 4;
  int* cur_prod = (int*)p; p += (size_t)NMET * 4;
  int* srce_sub = (int*)p; p += (size_t)E * 4;
  int* srce_shr = (int*)p; p += (size_t)E * 4;
  int* srce_prod = (int*)p; p += (size_t)E * 4;

  float* out_rxn = (float*)d_out;
  float* out_met = out_rxn + (size_t)NRXN * CDIM;

  // host-side threefry split (partitionable): subkey i = tf(key, (0, i))
  unsigned k1_0, k1_1, k2_0, k2_1;
  tf2x32(0u, 1u, 0u, 0u, k1_0, k1_1);
  tf2x32(0u, 1u, 0u, 1u, k2_0, k2_1);

  dim3 blk(256);

  // ---- CSR build (3 relations) ----
  hipMemsetAsync(cnt_sub, 0, (size_t)(NRXN + NRXN + NMET) * 4, stream);
  hist3<<<dim3((E + 255) / 256, 3), blk, 0, stream>>>(
      sub_dst, shr_dst, prod_dst, E, cnt_sub, cnt_shr, cnt_prod);
  scan3<<<3, 1024, 0, stream>>>(
      cnt_sub, cnt_shr, cnt_prod, off_sub, off_shr, off_prod,
      cur_sub, cur_shr, cur_prod, NRXN, NRXN, NMET);
  scatter3<<<dim3((E + 255) / 256, 3), blk, 0, stream>>>(
      sub_src, sub_dst, shr_src, shr_dst, prod_src, prod_dst, E,
      cur_sub, cur_shr, cur_prod, srce_sub, srce_shr, srce_prod);

  // ---- prep: convert + transpose ----
  cvt_bf16<<<(NMET * DDIM / 8 + 255) / 256, blk, 0, stream>>>(x_met, xmb, NMET * DDIM);
  cvt_bf16<<<(NRXN * DDIM / 8 + 255) / 256, blk, 0, stream>>>(x_rxn, xrb, NRXN * DDIM);
  wtrans<<<dim3(64, 8), blk, 0, stream>>>(
      Wl_sub, Wr_sub, Wl_shr, Wr_shr, Wl_prod, Wr_prod, W_proj_rxn, W_proj_met,
      wt[0], wt[1], wt[2], wt[3], wt[4], wt[5], wt[6], wt[7]);

  const int MT_MET = (NMET + 63) / 64, MT_RXN = (NRXN + 63) / 64;

  // projection GEMMs into d_out (scratch until finalize)
  gemm_mfma<float><<<(MT_RXN + 3) / 4, blk, 0, stream>>>(xrb, wt[6], b_proj_rxn, out_rxn, NRXN, CDIM);
  gemm_mfma<float><<<(MT_MET + 3) / 4, blk, 0, stream>>>(xmb, wt[7], b_proj_met, out_met, NMET, CDIM);

  // ---------- relation: substrate (met -> rxn) ----------
  gemm_mfma<__hip_bfloat16><<<(MT_MET * 4 + 3) / 4, blk, 0, stream>>>(xmb, wt[0], bl_sub, xl_bf, NMET, DDIM);
  gemm_mfma<__hip_bfloat16><<<(MT_RXN * 4 + 3) / 4, blk, 0, stream>>>(xrb, wt[1], br_sub, xr_bf, NRXN, DDIM);
  gat_node<<<(NRXN + 3) / 4, blk, 0, stream>>>(
      xl_bf, xr_bf, off_sub, srce_sub, att_sub, acc_sub, NRXN, 0);

  // ---------- relation: shared_metabolite (rxn -> rxn, self loops in-kernel) ----------
  gemm_mfma<__hip_bfloat16><<<(MT_RXN * 4 + 3) / 4, blk, 0, stream>>>(xrb, wt[2], bl_shr, xl_bf, NRXN, DDIM);
  gemm_mfma<__hip_bfloat16><<<(MT_RXN * 4 + 3) / 4, blk, 0, stream>>>(xrb, wt[3], br_shr, xr_bf, NRXN, DDIM);
  gat_node<<<(NRXN + 3) / 4, blk, 0, stream>>>(
      xl_bf, xr_bf, off_shr, srce_shr, att_shr, acc_shr, NRXN, 1);

  // ---------- relation: product (rxn -> met) ----------
  gemm_mfma<__hip_bfloat16><<<(MT_RXN * 4 + 3) / 4, blk, 0, stream>>>(xrb, wt[4], bl_prod, xl_bf, NRXN, DDIM);
  gemm_mfma<__hip_bfloat16><<<(MT_MET * 4 + 3) / 4, blk, 0, stream>>>(xmb, wt[5], br_prod, xr_bf, NMET, DDIM);
  gat_node<<<(NMET + 3) / 4, blk, 0, stream>>>(
      xl_bf, xr_bf, off_prod, srce_prod, att_prod, acc_met, NMET, 0);

  // ---------- finalize ----------
  finalize<<<(NRXN + 3) / 4, blk, 0, stream>>>(
      acc_sub, acc_shr, out_rxn, b_sub, b_shr, 0.5f, ln_rxn_g, ln_rxn_b,
      NRXN, k1_0, k1_1);
  finalize<<<(NMET + 3) / 4, blk, 0, stream>>>(
      acc_met, nullptr, out_met, b_prod, nullptr, 1.0f, ln_met_g, ln_met_b,
      NMET, k2_0, k2_1);
}

// Round 6
// 449.152 us; speedup vs baseline: 2.0856x; 1.1791x over previous
//
#include <hip/hip_runtime.h>
#include <hip/hip_bf16.h>
#include <stdint.h>

#define NMET 20000
#define NRXN 40000
#define DDIM 256
#define CDIM 64

typedef __attribute__((ext_vector_type(8))) short bf16x8;
typedef __attribute__((ext_vector_type(4))) float f32x4;

// ---------------- threefry2x32 (exact JAX semantics) ----------------
__host__ __device__ inline void tf2x32(unsigned k0, unsigned k1,
                                       unsigned x0, unsigned x1,
                                       unsigned &o0, unsigned &o1) {
  unsigned ks2 = k0 ^ k1 ^ 0x1BD11BDAu;
#define TFR(r) { x0 += x1; x1 = (x1 << r) | (x1 >> (32 - r)); x1 ^= x0; }
  x0 += k0; x1 += k1;
  TFR(13) TFR(15) TFR(26) TFR(6)
  x0 += k1; x1 += ks2 + 1u;
  TFR(17) TFR(29) TFR(16) TFR(24)
  x0 += ks2; x1 += k0 + 2u;
  TFR(13) TFR(15) TFR(26) TFR(6)
  x0 += k0; x1 += k1 + 3u;
  TFR(17) TFR(29) TFR(16) TFR(24)
  x0 += k1; x1 += ks2 + 4u;
  TFR(13) TFR(15) TFR(26) TFR(6)
  x0 += ks2; x1 += k0 + 5u;
#undef TFR
  o0 = x0; o1 = x1;
}

__device__ inline unsigned short f2bbits(float f) {
  __hip_bfloat16 h = __float2bfloat16(f);
  return *reinterpret_cast<unsigned short*>(&h);
}
__device__ inline float b2f(unsigned short u) {
  unsigned v = (unsigned)u << 16;
  return __uint_as_float(v);
}

// ---------------- fp32 -> bf16 convert (both inputs, one dispatch) ----------------
__global__ __launch_bounds__(256) void cvt_both(
    const float* __restrict__ a, __hip_bfloat16* __restrict__ oa, int na,
    const float* __restrict__ b, __hip_bfloat16* __restrict__ ob, int nb) {
  int i = (blockIdx.x * 256 + threadIdx.x) * 8;
  const float* in; __hip_bfloat16* out; int n;
  if (blockIdx.y == 0) { in = a; out = oa; n = na; }
  else { in = b; out = ob; n = nb; }
  if (i >= n) return;
  float4 va = *reinterpret_cast<const float4*>(in + i);
  float4 vb = *reinterpret_cast<const float4*>(in + i + 4);
  bf16x8 o;
  o[0] = (short)f2bbits(va.x); o[1] = (short)f2bbits(va.y);
  o[2] = (short)f2bbits(va.z); o[3] = (short)f2bbits(va.w);
  o[4] = (short)f2bbits(vb.x); o[5] = (short)f2bbits(vb.y);
  o[6] = (short)f2bbits(vb.z); o[7] = (short)f2bbits(vb.w);
  *reinterpret_cast<bf16x8*>(out + i) = o;
}

// ---------------- W[k][n] -> Wt[n][k] bf16, 8 matrices fused ----------------
__global__ __launch_bounds__(256) void wtrans(
    const float* w0, const float* w1, const float* w2, const float* w3,
    const float* w4, const float* w5, const float* w6, const float* w7,
    __hip_bfloat16* o0, __hip_bfloat16* o1, __hip_bfloat16* o2, __hip_bfloat16* o3,
    __hip_bfloat16* o4, __hip_bfloat16* o5, __hip_bfloat16* o6, __hip_bfloat16* o7) {
  int z = blockIdx.y;
  const float* w; __hip_bfloat16* o; int Ncols;
  switch (z) {
    case 0: w = w0; o = o0; Ncols = 256; break;
    case 1: w = w1; o = o1; Ncols = 256; break;
    case 2: w = w2; o = o2; Ncols = 256; break;
    case 3: w = w3; o = o3; Ncols = 256; break;
    case 4: w = w4; o = o4; Ncols = 256; break;
    case 5: w = w5; o = o5; Ncols = 256; break;
    case 6: w = w6; o = o6; Ncols = 64; break;
    default: w = w7; o = o7; Ncols = 64; break;
  }
  int ntile = Ncols / 32;
  int t = blockIdx.x;
  if (t >= ntile * 8) return;  // K=256 -> 8 k-tiles
  int tn = t % ntile, tk = t / ntile;
  __shared__ float ts[32][33];
  int tx = threadIdx.x & 31, ty = threadIdx.x >> 5;
#pragma unroll
  for (int r = ty; r < 32; r += 8)
    ts[r][tx] = w[(size_t)(tk * 32 + r) * Ncols + tn * 32 + tx];
  __syncthreads();
#pragma unroll
  for (int r = ty; r < 32; r += 8)
    o[(size_t)(tn * 32 + r) * 256 + tk * 32 + tx] = __float2bfloat16(ts[tx][r]);
}

// ---------------- multi-GEMM: up to 4 GEMMs per dispatch ----------------
struct GDesc {
  const __hip_bfloat16* X;
  const __hip_bfloat16* W;   // Wt[n][k]
  const float* bias;
  __hip_bfloat16* Yb;        // bf16 out (or null)
  float* Yf;                 // f32 out (or null)
  int M, N, tiles;
};

__device__ inline void gemm_tile(const GDesc& g, int tile, int lane) {
  int nt = g.N >> 6;
  int m0 = (tile / nt) * 64, n0 = (tile % nt) * 64;
  int lr = lane & 15, lk = lane >> 4;
  size_t arow[4], brow[4];
#pragma unroll
  for (int i = 0; i < 4; ++i) {
    int r = m0 + i * 16 + lr;
    if (r > g.M - 1) r = g.M - 1;
    arow[i] = (size_t)r * DDIM + lk * 8;
  }
#pragma unroll
  for (int j = 0; j < 4; ++j)
    brow[j] = (size_t)(n0 + j * 16 + lr) * DDIM + lk * 8;

  f32x4 acc[4][4] = {};
#pragma unroll
  for (int kt = 0; kt < 8; ++kt) {
    bf16x8 a[4], b[4];
#pragma unroll
    for (int i = 0; i < 4; ++i)
      a[i] = *reinterpret_cast<const bf16x8*>(g.X + arow[i] + kt * 32);
#pragma unroll
    for (int j = 0; j < 4; ++j)
      b[j] = *reinterpret_cast<const bf16x8*>(g.W + brow[j] + kt * 32);
#pragma unroll
    for (int i = 0; i < 4; ++i)
#pragma unroll
      for (int j = 0; j < 4; ++j)
        acc[i][j] = __builtin_amdgcn_mfma_f32_16x16x32_bf16(a[i], b[j], acc[i][j], 0, 0, 0);
  }
  bool isb = (g.Yb != nullptr);
#pragma unroll
  for (int i = 0; i < 4; ++i) {
#pragma unroll
    for (int r = 0; r < 4; ++r) {
      int row = m0 + i * 16 + lk * 4 + r;
      if (row >= g.M) continue;
#pragma unroll
      for (int j = 0; j < 4; ++j) {
        int col = n0 + j * 16 + lr;
        float v = acc[i][j][r] + g.bias[col];
        if (isb) g.Yb[(size_t)row * g.N + col] = __float2bfloat16(v);
        else     g.Yf[(size_t)row * g.N + col] = v;
      }
    }
  }
}

__global__ __launch_bounds__(256) void gemm_multi(GDesc g0, GDesc g1, GDesc g2, GDesc g3, int ng) {
  int wave = threadIdx.x >> 6, lane = threadIdx.x & 63;
  int t = blockIdx.x * 4 + wave;
  if (t < g0.tiles) { gemm_tile(g0, t, lane); return; }
  t -= g0.tiles;
  if (ng < 2) return;
  if (t < g1.tiles) { gemm_tile(g1, t, lane); return; }
  t -= g1.tiles;
  if (ng < 3) return;
  if (t < g2.tiles) { gemm_tile(g2, t, lane); return; }
  t -= g2.tiles;
  if (ng < 4) return;
  if (t < g3.tiles) { gemm_tile(g3, t, lane); return; }
}

// ---------------- CSR build: histogram over 3 relations ----------------
__global__ __launch_bounds__(256) void hist3(
    const int* __restrict__ d0, const int* __restrict__ d1, const int* __restrict__ d2,
    int E, int* __restrict__ c0, int* __restrict__ c1, int* __restrict__ c2) {
  int i = blockIdx.x * 256 + threadIdx.x;
  if (i >= E) return;
  int rel = blockIdx.y;
  if (rel == 0) atomicAdd(&c0[d0[i]], 1);
  else if (rel == 1) atomicAdd(&c1[d1[i]], 1);
  else atomicAdd(&c2[d2[i]], 1);
}

// ---------------- range allocation via atomic cursor (replaces scan) ----------------
__global__ __launch_bounds__(256) void alloc3(
    const int* __restrict__ c0, const int* __restrict__ c1, const int* __restrict__ c2,
    int* __restrict__ o0, int* __restrict__ o1, int* __restrict__ o2,
    int* __restrict__ u0, int* __restrict__ u1, int* __restrict__ u2,
    int* __restrict__ cursors, int n0, int n1, int n2) {
  int rel = blockIdx.y;
  int i = blockIdx.x * 256 + threadIdx.x;
  const int* c = (rel == 0) ? c0 : (rel == 1) ? c1 : c2;
  int* o = (rel == 0) ? o0 : (rel == 1) ? o1 : o2;
  int* u = (rel == 0) ? u0 : (rel == 1) ? u1 : u2;
  int n = (rel == 0) ? n0 : (rel == 1) ? n1 : n2;
  if (i >= n) return;
  int cc = c[i];
  int pos = atomicAdd(&cursors[rel], cc);
  o[i] = pos; u[i] = pos;
}

// ---------------- CSR build: scatter source ids ----------------
__global__ __launch_bounds__(256) void scatter3(
    const int* __restrict__ s0, const int* __restrict__ d0,
    const int* __restrict__ s1, const int* __restrict__ d1,
    const int* __restrict__ s2, const int* __restrict__ d2,
    int E, int* __restrict__ u0, int* __restrict__ u1, int* __restrict__ u2,
    int* __restrict__ e0, int* __restrict__ e1, int* __restrict__ e2) {
  int i = blockIdx.x * 256 + threadIdx.x;
  if (i >= E) return;
  int rel = blockIdx.y;
  if (rel == 0)      { int pos = atomicAdd(&u0[d0[i]], 1); e0[pos] = s0[i]; }
  else if (rel == 1) { int pos = atomicAdd(&u1[d1[i]], 1); e1[pos] = s1[i]; }
  else               { int pos = atomicAdd(&u2[d2[i]], 1); e2[pos] = s2[i]; }
}

// ---------------- fused GATv2 per destination node (online softmax) ----------------
// wave per dst: lane l holds flat channels [4l,4l+3] = head l>>4
__global__ __launch_bounds__(256) void gat_node(
    const __hip_bfloat16* __restrict__ xl, const __hip_bfloat16* __restrict__ xr,
    const int* __restrict__ off, const int* __restrict__ cnt,
    const int* __restrict__ srce,
    const float* __restrict__ att, float* __restrict__ accout,
    int n, int self_loop) {
  int d = blockIdx.x * 4 + (threadIdx.x >> 6);
  int lane = threadIdx.x & 63;
  if (d >= n) return;
  int beg = off[d];
  int total = cnt[d] + self_loop;

  ushort4 ur = *reinterpret_cast<const ushort4*>(xr + (size_t)d * DDIM + 4 * lane);
  float r0 = b2f(ur.x), r1 = b2f(ur.y), r2 = b2f(ur.z), r3 = b2f(ur.w);
  float4 at = *reinterpret_cast<const float4*>(att + 4 * lane);

  float m = -INFINITY, den = 0.f;
  float a0 = 0.f, a1 = 0.f, a2 = 0.f, a3 = 0.f;
  for (int it = 0; it < total; ++it) {
    int s = (self_loop && it == 0) ? d : srce[beg + it - self_loop];
    ushort4 ux = *reinterpret_cast<const ushort4*>(xl + (size_t)s * DDIM + 4 * lane);
    float x0 = b2f(ux.x), x1 = b2f(ux.y), x2 = b2f(ux.z), x3 = b2f(ux.w);
    float t0 = x0 + r0; t0 = (t0 >= 0.f) ? t0 : 0.2f * t0;
    float t1 = x1 + r1; t1 = (t1 >= 0.f) ? t1 : 0.2f * t1;
    float t2 = x2 + r2; t2 = (t2 >= 0.f) ? t2 : 0.2f * t2;
    float t3 = x3 + r3; t3 = (t3 >= 0.f) ? t3 : 0.2f * t3;
    float p = t0 * at.x + t1 * at.y + t2 * at.z + t3 * at.w;
    p += __shfl_xor(p, 1);
    p += __shfl_xor(p, 2);
    p += __shfl_xor(p, 4);
    p += __shfl_xor(p, 8);
    float nm = fmaxf(m, p);
    float sc = __expf(m - nm);   // first iter: exp(-inf)=0
    float ex = __expf(p - nm);
    den = den * sc + ex;
    a0 = a0 * sc + ex * x0;
    a1 = a1 * sc + ex * x1;
    a2 = a2 * sc + ex * x2;
    a3 = a3 * sc + ex * x3;
    m = nm;
  }
  float inv = (den > 0.f) ? 1.0f / den : 0.f;
  float p0 = a0 * inv, p1 = a1 * inv, p2 = a2 * inv, p3 = a3 * inv;
  // mean over 4 heads: sum groups (lanes l, l+16, l+32, l+48), then redistribute
  p0 += __shfl_xor(p0, 16); p0 += __shfl_xor(p0, 32);
  p1 += __shfl_xor(p1, 16); p1 += __shfl_xor(p1, 32);
  p2 += __shfl_xor(p2, 16); p2 += __shfl_xor(p2, 32);
  p3 += __shfl_xor(p3, 16); p3 += __shfl_xor(p3, 32);
  int srcl = lane >> 2;
  float v0 = __shfl(p0, srcl);
  float v1 = __shfl(p1, srcl);
  float v2 = __shfl(p2, srcl);
  float v3 = __shfl(p3, srcl);
  float val = (lane & 2) ? ((lane & 1) ? v3 : v2) : ((lane & 1) ? v1 : v0);
  accout[(size_t)d * 64 + lane] = 0.25f * val;
}

// ---------------- finalize: elu + residual + LN + threefry dropout ----------------
__global__ __launch_bounds__(256) void finalize(
    const float* __restrict__ accA, const float* __restrict__ accB,
    float* __restrict__ out,
    const float* __restrict__ bA, const float* __restrict__ bB, float scale,
    const float* __restrict__ g, const float* __restrict__ beta,
    int Nn, unsigned key0, unsigned key1) {
  int w = blockIdx.x * 4 + (threadIdx.x >> 6);
  int lane = threadIdx.x & 63;
  if (w >= Nn) return;
  unsigned idx = (unsigned)w * 64u + (unsigned)lane;
  float bias = bA[lane] + (bB ? bB[lane] : 0.f);
  float agg = accA[idx] + (accB ? accB[idx] : 0.f);
  float pre = scale * (agg + bias);
  pre = (pre > 0.f) ? pre : expm1f(pre);  // elu
  pre += out[idx];                        // + proj (bias already added)
  float mu = pre;
#pragma unroll
  for (int off = 32; off; off >>= 1) mu += __shfl_xor(mu, off);
  mu *= (1.0f / 64.0f);
  float dv = pre - mu;
  float var = dv * dv;
#pragma unroll
  for (int off = 32; off; off >>= 1) var += __shfl_xor(var, off);
  var *= (1.0f / 64.0f);
  float y = dv * rsqrtf(var + 1e-5f) * g[lane] + beta[lane];
  unsigned o0, o1;
  tf2x32(key0, key1, 0u, idx, o0, o1);
  unsigned bits = o0 ^ o1;
  float u = __uint_as_float((bits >> 9) | 0x3f800000u) - 1.0f;
  y = (u < 0.8f) ? y / 0.8f : 0.0f;
  out[idx] = y;
}

// ---------------- launch ----------------
extern "C" void kernel_launch(void* const* d_in, const int* in_sizes, int n_in,
                              void* d_out, int out_size, void* d_ws, size_t ws_size,
                              hipStream_t stream) {
  const float* x_met = (const float*)d_in[0];
  const float* x_rxn = (const float*)d_in[1];
  const int* sub_src = (const int*)d_in[2];
  const int* sub_dst = (const int*)d_in[3];
  const int* prod_src = (const int*)d_in[4];
  const int* prod_dst = (const int*)d_in[5];
  const int* shr_src = (const int*)d_in[6];
  const int* shr_dst = (const int*)d_in[7];
  const float* Wl_sub = (const float*)d_in[8];
  const float* bl_sub = (const float*)d_in[9];
  const float* Wr_sub = (const float*)d_in[10];
  const float* br_sub = (const float*)d_in[11];
  const float* att_sub = (const float*)d_in[12];
  const float* b_sub = (const float*)d_in[13];
  const float* Wl_prod = (const float*)d_in[14];
  const float* bl_prod = (const float*)d_in[15];
  const float* Wr_prod = (const float*)d_in[16];
  const float* br_prod = (const float*)d_in[17];
  const float* att_prod = (const float*)d_in[18];
  const float* b_prod = (const float*)d_in[19];
  const float* Wl_shr = (const float*)d_in[20];
  const float* bl_shr = (const float*)d_in[21];
  const float* Wr_shr = (const float*)d_in[22];
  const float* br_shr = (const float*)d_in[23];
  const float* att_shr = (const float*)d_in[24];
  const float* b_shr = (const float*)d_in[25];
  const float* W_proj_rxn = (const float*)d_in[26];
  const float* b_proj_rxn = (const float*)d_in[27];
  const float* W_proj_met = (const float*)d_in[28];
  const float* b_proj_met = (const float*)d_in[29];
  const float* ln_rxn_g = (const float*)d_in[30];
  const float* ln_rxn_b = (const float*)d_in[31];
  const float* ln_met_g = (const float*)d_in[32];
  const float* ln_met_b = (const float*)d_in[33];

  const int E = in_sizes[2];  // 250000

  // workspace carve (bytes)
  char* p = (char*)d_ws;
  __hip_bfloat16* xmb = (__hip_bfloat16*)p; p += (size_t)NMET * DDIM * 2;
  __hip_bfloat16* xrb = (__hip_bfloat16*)p; p += (size_t)NRXN * DDIM * 2;
  __hip_bfloat16* wt[8];
  for (int i = 0; i < 6; ++i) { wt[i] = (__hip_bfloat16*)p; p += 256 * 256 * 2; }
  for (int i = 6; i < 8; ++i) { wt[i] = (__hip_bfloat16*)p; p += 64 * 256 * 2; }
  __hip_bfloat16* xl_bf = (__hip_bfloat16*)p; p += (size_t)NRXN * DDIM * 2;
  __hip_bfloat16* xr_bf = (__hip_bfloat16*)p; p += (size_t)NRXN * DDIM * 2;
  float* acc_sub = (float*)p; p += (size_t)NRXN * CDIM * 4;
  float* acc_shr = (float*)p; p += (size_t)NRXN * CDIM * 4;
  float* acc_met = (float*)p; p += (size_t)NMET * CDIM * 4;
  // CSR arrays (cnt_* then cursors contiguous for one memset)
  int* cnt_sub = (int*)p; p += (size_t)NRXN * 4;
  int* cnt_shr = (int*)p; p += (size_t)NRXN * 4;
  int* cnt_prod = (int*)p; p += (size_t)NMET * 4;
  int* cursors = (int*)p; p += 4 * 4;
  int* off_sub = (int*)p; p += (size_t)NRXN * 4;
  int* off_shr = (int*)p; p += (size_t)NRXN * 4;
  int* off_prod = (int*)p; p += (size_t)NMET * 4;
  int* cur_sub = (int*)p; p += (size_t)NRXN * 4;
  int* cur_shr = (int*)p; p += (size_t)NRXN * 4;
  int* cur_prod = (int*)p; p += (size_t)NMET * 4;
  int* srce_sub = (int*)p; p += (size_t)E * 4;
  int* srce_shr = (int*)p; p += (size_t)E * 4;
  int* srce_prod = (int*)p; p += (size_t)E * 4;

  float* out_rxn = (float*)d_out;
  float* out_met = out_rxn + (size_t)NRXN * CDIM;

  // host-side threefry split (partitionable): subkey i = tf(key, (0, i))
  unsigned k1_0, k1_1, k2_0, k2_1;
  tf2x32(0u, 1u, 0u, 0u, k1_0, k1_1);
  tf2x32(0u, 1u, 0u, 1u, k2_0, k2_1);

  dim3 blk(256);

  // ---- CSR build (3 relations), scan-free ----
  hipMemsetAsync(cnt_sub, 0, ((size_t)(NRXN + NRXN + NMET) + 4) * 4, stream);
  hist3<<<dim3((E + 255) / 256, 3), blk, 0, stream>>>(
      sub_dst, shr_dst, prod_dst, E, cnt_sub, cnt_shr, cnt_prod);
  alloc3<<<dim3((NRXN + 255) / 256, 3), blk, 0, stream>>>(
      cnt_sub, cnt_shr, cnt_prod, off_sub, off_shr, off_prod,
      cur_sub, cur_shr, cur_prod, cursors, NRXN, NRXN, NMET);
  scatter3<<<dim3((E + 255) / 256, 3), blk, 0, stream>>>(
      sub_src, sub_dst, shr_src, shr_dst, prod_src, prod_dst, E,
      cur_sub, cur_shr, cur_prod, srce_sub, srce_shr, srce_prod);

  // ---- prep: convert + transpose ----
  cvt_both<<<dim3((NRXN * DDIM / 8 + 255) / 256, 2), blk, 0, stream>>>(
      x_met, xmb, NMET * DDIM, x_rxn, xrb, NRXN * DDIM);
  wtrans<<<dim3(64, 8), blk, 0, stream>>>(
      Wl_sub, Wr_sub, Wl_shr, Wr_shr, Wl_prod, Wr_prod, W_proj_rxn, W_proj_met,
      wt[0], wt[1], wt[2], wt[3], wt[4], wt[5], wt[6], wt[7]);

  const int MT_MET = (NMET + 63) / 64, MT_RXN = (NRXN + 63) / 64;

  auto mkdesc = [](const __hip_bfloat16* X, const __hip_bfloat16* W, const float* bias,
                   __hip_bfloat16* Yb, float* Yf, int M, int N) {
    GDesc g; g.X = X; g.W = W; g.bias = bias; g.Yb = Yb; g.Yf = Yf;
    g.M = M; g.N = N; g.tiles = ((M + 63) / 64) * (N / 64);
    return g;
  };

  // ---- dispatch 1: proj_rxn, proj_met, sub_xl, sub_xr ----
  {
    GDesc g0 = mkdesc(xrb, wt[6], b_proj_rxn, nullptr, out_rxn, NRXN, CDIM);
    GDesc g1 = mkdesc(xmb, wt[7], b_proj_met, nullptr, out_met, NMET, CDIM);
    GDesc g2 = mkdesc(xmb, wt[0], bl_sub, xl_bf, nullptr, NMET, DDIM);
    GDesc g3 = mkdesc(xrb, wt[1], br_sub, xr_bf, nullptr, NRXN, DDIM);
    int tot = g0.tiles + g1.tiles + g2.tiles + g3.tiles;
    gemm_multi<<<(tot + 3) / 4, blk, 0, stream>>>(g0, g1, g2, g3, 4);
  }
  gat_node<<<(NRXN + 3) / 4, blk, 0, stream>>>(
      xl_bf, xr_bf, off_sub, cnt_sub, srce_sub, att_sub, acc_sub, NRXN, 0);

  // ---- dispatch 2: shr pair ----
  {
    GDesc g0 = mkdesc(xrb, wt[2], bl_shr, xl_bf, nullptr, NRXN, DDIM);
    GDesc g1 = mkdesc(xrb, wt[3], br_shr, xr_bf, nullptr, NRXN, DDIM);
    int tot = g0.tiles + g1.tiles;
    gemm_multi<<<(tot + 3) / 4, blk, 0, stream>>>(g0, g1, g1, g1, 2);
  }
  gat_node<<<(NRXN + 3) / 4, blk, 0, stream>>>(
      xl_bf, xr_bf, off_shr, cnt_shr, srce_shr, att_shr, acc_shr, NRXN, 1);

  // ---- dispatch 3: prod pair ----
  {
    GDesc g0 = mkdesc(xrb, wt[4], bl_prod, xl_bf, nullptr, NRXN, DDIM);
    GDesc g1 = mkdesc(xmb, wt[5], br_prod, xr_bf, nullptr, NMET, DDIM);
    int tot = g0.tiles + g1.tiles;
    gemm_multi<<<(tot + 3) / 4, blk, 0, stream>>>(g0, g1, g1, g1, 2);
  }
  gat_node<<<(NMET + 3) / 4, blk, 0, stream>>>(
      xl_bf, xr_bf, off_prod, cnt_prod, srce_prod, att_prod, acc_met, NMET, 0);

  // ---------- finalize ----------
  finalize<<<(NRXN + 3) / 4, blk, 0, stream>>>(
      acc_sub, acc_shr, out_rxn, b_sub, b_shr, 0.5f, ln_rxn_g, ln_rxn_b,
      NRXN, k1_0, k1_1);
  finalize<<<(NMET + 3) / 4, blk, 0, stream>>>(
      acc_met, nullptr, out_met, b_prod, nullptr, 1.0f, ln_met_g, ln_met_b,
      NMET, k2_0, k2_1);
}